// Round 7
// baseline (126.289 us; speedup 1.0000x reference)
//
#include <hip/hip_runtime.h>

#define D_M     64
#define L_OBS   256
#define ALPHA   256
#define D_H     256
#define D_V     64
#define N_HEADS 8

// ---------------------------------------------------------------------------
// Kernel 1: prep. Blocks 0..63: per-row imputation. Blocks 64..191: per-(h,
// 16-a-chunk) fold: Qa = theta_a . wq^T + wq_b, then QW[d][a] = Qa . wk[.][d].
// (All a-row-constant score terms are dropped: softmax is shift-invariant.)
// ---------------------------------------------------------------------------
__global__ __launch_bounds__(256) void prep_kernel(
    const float* __restrict__ x_ts, const float* __restrict__ t_ts,
    const float* __restrict__ gm,
    const float* __restrict__ t2v_w, const float* __restrict__ t2v_phi,
    const float* __restrict__ wq_w, const float* __restrict__ wq_b,
    const float* __restrict__ wk_w,
    float* __restrict__ regular, float* __restrict__ QWbuf)
{
    const int tid = threadIdx.x;

    __shared__ int   last[ALPHA];
    __shared__ float vals[ALPHA];
    __shared__ int   pos[ALPHA];
    __shared__ __align__(16) float wq_s[D_V][68];
    __shared__ __align__(16) float thA[16][68];
    __shared__ __align__(16) float QaT[16][68];

    if (blockIdx.x < D_M) {
        // ---------------- imputation ----------------
        const int m = blockIdx.x;
        const int l = tid;
        last[l] = -1;
        __syncthreads();
        float x = x_ts[m * L_OBS + l];
        float t = t_ts[m * L_OBS + l];
        bool valid = (x == x) && (t >= 0.0f);
        int idx = (int)t;
        if (valid && idx < ALPHA) atomicMax(&last[idx], l);
        __syncthreads();
        int li = last[l];
        vals[l] = (li >= 0) ? x_ts[m * L_OBS + li] : 0.0f;
        pos[l]  = (li >= 0) ? l : -1;
        __syncthreads();
        for (int off = 1; off < ALPHA; off <<= 1) {
            int v = (l >= off) ? pos[l - off] : -1;
            __syncthreads();
            if (v > pos[l]) pos[l] = v;
            __syncthreads();
        }
        int lp = pos[l];
        regular[m * ALPHA + l] = (lp >= 0) ? vals[lp] : gm[m];
    } else {
        // ---------------- weight fold + QW for 16 a ----------------
        const int p  = blockIdx.x - D_M;   // 0..127
        const int h  = p >> 4;
        const int a0 = (p & 15) * 16;

        {
            const float4* w4 = (const float4*)(wq_w + h * D_V * D_V);
            #pragma unroll
            for (int i = 0; i < 4; i++) {
                int f = i * 256 + tid;
                float4 v = w4[f];
                int e = f >> 4, c = (f & 15) * 4;
                *(float4*)&wq_s[e][c] = v;
            }
        }
        {
            int al = tid >> 4, j0 = (tid & 15) * 4;
            float tv = (float)(a0 + al);
            #pragma unroll
            for (int j = 0; j < 4; j++) {
                int d = j0 + j;
                float f = t2v_w[h * D_V + d] * tv + t2v_phi[h * D_V + d];
                thA[al][d] = (d == 0) ? f : __sinf(f);
            }
        }
        __syncthreads();

        // Phase A: QaT[a][e] = thA[a] . wq_s[e] + wq_b[e]
        {
            const int e  = tid >> 2;
            const int ap = tid & 3;
            float accA[4] = {0.f, 0.f, 0.f, 0.f};
            const float4* wrow = (const float4*)&wq_s[e][0];
            #pragma unroll
            for (int j = 0; j < 16; j++) {
                float4 w = wrow[j];
                #pragma unroll
                for (int k = 0; k < 4; k++) {
                    float4 tv = *(const float4*)&thA[ap + 4 * k][j * 4];
                    accA[k] += w.x * tv.x + w.y * tv.y + w.z * tv.z + w.w * tv.w;
                }
            }
            float bq = wq_b[h * D_V + e];
            #pragma unroll
            for (int k = 0; k < 4; k++) QaT[ap + 4 * k][e] = accA[k] + bq;
        }
        __syncthreads();

        // Phase B: QW[d][a] = sum_e QaT[a][e] * wk_w[h][e][d]
        {
            const int d  = tid >> 2;
            const int ap = tid & 3;
            float accB[4] = {0.f, 0.f, 0.f, 0.f};
            #pragma unroll 4
            for (int e4 = 0; e4 < 16; e4++) {
                const float* wkp = &wk_w[(h * D_V + e4 * 4) * D_V + d];
                float w0 = wkp[0];
                float w1 = wkp[D_V];
                float w2 = wkp[2 * D_V];
                float w3 = wkp[3 * D_V];
                #pragma unroll
                for (int k = 0; k < 4; k++) {
                    float4 qv = *(const float4*)&QaT[ap + 4 * k][e4 * 4];
                    accB[k] += qv.x * w0 + qv.y * w1 + qv.z * w2 + qv.w * w3;
                }
            }
            #pragma unroll
            for (int k = 0; k < 4; k++)
                QWbuf[h * D_V * ALPHA + d * ALPHA + a0 + ap + 4 * k] = accB[k];
        }
    }
}

// ---------------------------------------------------------------------------
// Kernel 2: fused mTAND attention, compacted, SGPR-operand inner loop.
// Grid (2 a-halves, 64 m, 8 h) = 1024 blocks (4/CU), 256 thr, LDS ~35 KB,
// launch_bounds(256,4) -> 16 waves/CU.
// lane = compacted-l slot within a 64-l supertile; each wave owns 2 chunks
// of 16 a. QW[d][a0:a0+16] is wave-uniform -> s_load (SMEM pipe); theta from
// LDS via 1 ds_read_b32 per d (2-way bank, free). Per d: 1 LDS + 16 v_fmac
// (SGPR x VGPR). Online softmax lane-local per a; one 64-lane merge/chunk.
// theta tile [64][128] with a pass loop (2 supertiles/pass) handles any Lv.
// ---------------------------------------------------------------------------
__global__ __launch_bounds__(256, 4) void attn_fused_kernel(
    const float* __restrict__ x_ts, const float* __restrict__ t_ts,
    const float* __restrict__ t2v_w, const float* __restrict__ t2v_phi,
    const float* __restrict__ QWbuf, float* __restrict__ interp)
{
    const int ah  = blockIdx.x;          // a-half
    const int m   = blockIdx.y;
    const int h   = blockIdx.z;
    const int tid = threadIdx.x;
    const int wv  = tid >> 6;
    const int ln  = tid & 63;

    __shared__ __align__(16) float tht[D_V][128];   // 32 KiB
    __shared__ float xc[L_OBS], tc[L_OBS];
    __shared__ float t2vw_s[D_V], t2vp_s[D_V];
    __shared__ int   cnt_s[4];

    // stage t2v, init compacted arrays
    if (tid < D_V)            t2vw_s[tid]        = t2v_w[h * D_V + tid];
    else if (tid < 2 * D_V)   t2vp_s[tid - D_V]  = t2v_phi[h * D_V + tid - D_V];
    xc[tid] = 0.0f;
    tc[tid] = 0.0f;

    // load obs, ballot-compact
    float x = x_ts[m * L_OBS + tid];
    float t = t_ts[m * L_OBS + tid];
    bool  v = (x == x) && (t >= 0.0f);
    unsigned long long bal = __ballot(v);
    if (ln == 0) cnt_s[wv] = __popcll(bal);
    __syncthreads();
    const int c0 = cnt_s[0], c1 = cnt_s[1], c2 = cnt_s[2], c3 = cnt_s[3];
    const int Lv = c0 + c1 + c2 + c3;
    {
        int base = (wv > 0 ? c0 : 0) + (wv > 1 ? c1 : 0) + (wv > 2 ? c2 : 0);
        unsigned long long lm = (1ull << ln) - 1ull;
        if (v) { int p = base + __popcll(bal & lm); xc[p] = x; tc[p] = t; }
    }
    __syncthreads();

    const int nst   = (Lv > 0) ? ((Lv + 63) >> 6) : 1;
    const int npass = (nst + 1) >> 1;
    const float SCALE2 = 0.18033688011112042f;   // 0.125 * log2(e)

    // theta-fill thread mapping
    const int lc = tid & 127;
    const int dg = (tid >> 7) * 32;

    for (int ck = 0; ck < 2; ck++) {
        const int chunk = ah * 8 + ck * 4 + wv;   // 16 chunks of 16 a
        const int a0 = chunk * 16;
        const int qbase = __builtin_amdgcn_readfirstlane(h * D_V * ALPHA + a0);

        float mrun[16], ssum[16], axs[16];
        #pragma unroll
        for (int i = 0; i < 16; i++) { mrun[i] = -3.0e38f; ssum[i] = 0.f; axs[i] = 0.f; }

        for (int pass = 0; pass < npass; pass++) {
            // ---- fill theta[64][128] for supertiles 2*pass, 2*pass+1 ----
            {
                float tval = tc[pass * 128 + lc];
                #pragma unroll
                for (int dd = 0; dd < 32; dd++) {
                    int d = dg + dd;
                    float f = t2vw_s[d] * tval + t2vp_s[d];
                    tht[d][lc] = (d == 0) ? f : __sinf(f);
                }
            }
            __syncthreads();

            const int stmax = (nst - pass * 2 < 2) ? (nst - pass * 2) : 2;
            for (int stl = 0; stl < stmax; stl++) {
                const int st = pass * 2 + stl;
                const int stl64 = stl * 64;
                float acc[16];
                #pragma unroll
                for (int j = 0; j < 16; j++) acc[j] = 0.f;

                const float* __restrict__ qp0 = QWbuf + qbase;
                #pragma unroll 4
                for (int d = 0; d < D_V; d++) {
                    float th = tht[d][stl64 + ln];
                    const float* qp = qp0 + d * ALPHA;   // wave-uniform -> s_load
                    #pragma unroll
                    for (int j = 0; j < 16; j++)
                        acc[j] = fmaf(qp[j], th, acc[j]);
                }

                float xv = xc[st * 64 + ln];
                float mk = (st * 64 + ln < Lv) ? 0.0f : -1.0e9f;
                #pragma unroll
                for (int i = 0; i < 16; i++) {
                    float s    = fmaf(acc[i], SCALE2, mk);
                    float mnew = fmaxf(mrun[i], s);
                    float scl  = __builtin_amdgcn_exp2f(mrun[i] - mnew);
                    float p    = __builtin_amdgcn_exp2f(s - mnew);
                    ssum[i] = fmaf(ssum[i], scl, p);
                    axs[i]  = fmaf(axs[i],  scl, p * xv);
                    mrun[i] = mnew;
                }
            }
            __syncthreads();   // theta overwrite / next-chunk guard
        }

        // ---- 64-lane merge per a, write interp [a][m][h] ----
        #pragma unroll
        for (int i = 0; i < 16; i++) {
            float m0 = mrun[i];
            m0 = fmaxf(m0, __shfl_xor(m0, 1));
            m0 = fmaxf(m0, __shfl_xor(m0, 2));
            m0 = fmaxf(m0, __shfl_xor(m0, 4));
            m0 = fmaxf(m0, __shfl_xor(m0, 8));
            m0 = fmaxf(m0, __shfl_xor(m0, 16));
            m0 = fmaxf(m0, __shfl_xor(m0, 32));
            float f = __builtin_amdgcn_exp2f(mrun[i] - m0);
            float S = ssum[i] * f;
            float A = axs[i] * f;
            S += __shfl_xor(S, 1);  A += __shfl_xor(A, 1);
            S += __shfl_xor(S, 2);  A += __shfl_xor(A, 2);
            S += __shfl_xor(S, 4);  A += __shfl_xor(A, 4);
            S += __shfl_xor(S, 8);  A += __shfl_xor(A, 8);
            S += __shfl_xor(S, 16); A += __shfl_xor(A, 16);
            S += __shfl_xor(S, 32); A += __shfl_xor(A, 32);
            if (ln == i)
                interp[(a0 + i) * (D_M * N_HEADS) + m * N_HEADS + h] = A / S;
        }
    }
}

// ---------------------------------------------------------------------------
// Kernel 3: fused e_imp + e_attn + gate MLP + output. Block per a, 256 thr.
// ---------------------------------------------------------------------------
__global__ __launch_bounds__(256) void final_kernel(
    const float* __restrict__ regular, const float* __restrict__ interp,
    const float* __restrict__ conv_w, const float* __restrict__ conv_b,
    const float* __restrict__ proj_w, const float* __restrict__ proj_b,
    const float* __restrict__ g1_w, const float* __restrict__ g1_b,
    const float* __restrict__ g2_w, const float* __restrict__ g2_b,
    float* __restrict__ out)
{
    const int a = blockIdx.x;
    const int tid = threadIdx.x;
    __shared__ float isum_s[N_HEADS];
    __shared__ __align__(16) float col[D_M];
    __shared__ __align__(16) float c_s[2 * D_H];
    __shared__ __align__(16) float h_s[D_H];

    if (tid < 64) {
        const float4* i4 = (const float4*)&interp[a * (D_M * N_HEADS) + tid * 8];
        float4 v0 = i4[0], v1 = i4[1];
        float v[8] = {v0.x, v0.y, v0.z, v0.w, v1.x, v1.y, v1.z, v1.w};
        #pragma unroll
        for (int s = 1; s < 64; s <<= 1) {
            #pragma unroll
            for (int j = 0; j < 8; j++) v[j] += __shfl_xor(v[j], s);
        }
        if (tid == 0) {
            #pragma unroll
            for (int j = 0; j < 8; j++) isum_s[j] = v[j];
        }
    } else if (tid < 128) {
        col[tid - 64] = regular[(tid - 64) * ALPHA + a];
    }
    __syncthreads();

    float vattn;
    {
        const float4* p4 = (const float4*)&proj_w[tid * N_HEADS];
        float4 v0 = p4[0], v1 = p4[1];
        float sum = v0.x * isum_s[0] + v0.y * isum_s[1] + v0.z * isum_s[2]
                  + v0.w * isum_s[3] + v1.x * isum_s[4] + v1.y * isum_s[5]
                  + v1.z * isum_s[6] + v1.w * isum_s[7];
        vattn = proj_b[tid] + sum * (1.0f / 64.0f);
    }
    float vimp;
    {
        const float4* row = (const float4*)&conv_w[tid * D_M];
        const float4* c4  = (const float4*)col;
        float s0 = 0.f, s1 = 0.f, s2 = 0.f, s3 = 0.f;
        #pragma unroll
        for (int i = 0; i < D_M / 4; i++) {
            float4 r = row[i]; float4 c = c4[i];
            s0 += r.x * c.x; s1 += r.y * c.y; s2 += r.z * c.z; s3 += r.w * c.w;
        }
        vimp = conv_b[tid] + ((s0 + s1) + (s2 + s3));
    }
    c_s[tid]       = vimp;
    c_s[D_H + tid] = vattn;
    __syncthreads();

    {
        const float4* grow = (const float4*)&g1_w[tid * 2 * D_H];
        const float4* c4 = (const float4*)c_s;
        float s0 = 0.f, s1 = 0.f, s2 = 0.f, s3 = 0.f;
        #pragma unroll 8
        for (int i = 0; i < (2 * D_H) / 4; i++) {
            float4 g = grow[i]; float4 c = c4[i];
            s0 += g.x * c.x; s1 += g.y * c.y; s2 += g.z * c.z; s3 += g.w * c.w;
        }
        float hid = g1_b[tid] + ((s0 + s1) + (s2 + s3));
        h_s[tid] = fmaxf(hid, 0.0f);
    }
    __syncthreads();
    {
        const float4* grow = (const float4*)&g2_w[tid * D_H];
        const float4* h4 = (const float4*)h_s;
        float s0 = 0.f, s1 = 0.f, s2 = 0.f, s3 = 0.f;
        #pragma unroll 8
        for (int i = 0; i < D_H / 4; i++) {
            float4 g = grow[i]; float4 hh = h4[i];
            s0 += g.x * hh.x; s1 += g.y * hh.y; s2 += g.z * hh.z; s3 += g.w * hh.w;
        }
        float z = g2_b[tid] + ((s0 + s1) + (s2 + s3));
        float gate = 1.0f / (1.0f + __expf(-z));
        out[a * D_H + tid] = gate * vimp + (1.0f - gate) * vattn;
    }
}

// ---------------------------------------------------------------------------
extern "C" void kernel_launch(void* const* d_in, const int* in_sizes, int n_in,
                              void* d_out, int out_size, void* d_ws, size_t ws_size,
                              hipStream_t stream)
{
    (void)in_sizes; (void)n_in; (void)out_size; (void)ws_size;

    const float* x_ts    = (const float*)d_in[0];
    const float* t_ts    = (const float*)d_in[1];
    const float* gm      = (const float*)d_in[2];
    const float* conv_w  = (const float*)d_in[3];
    const float* conv_b  = (const float*)d_in[4];
    const float* t2v_w   = (const float*)d_in[5];
    const float* t2v_phi = (const float*)d_in[6];
    const float* wq_w    = (const float*)d_in[7];
    const float* wq_b    = (const float*)d_in[8];
    const float* wk_w    = (const float*)d_in[9];
    const float* proj_w  = (const float*)d_in[11];
    const float* proj_b  = (const float*)d_in[12];
    const float* g1_w    = (const float*)d_in[13];
    const float* g1_b    = (const float*)d_in[14];
    const float* g2_w    = (const float*)d_in[15];
    const float* g2_b    = (const float*)d_in[16];

    float* out = (float*)d_out;

    float* ws      = (float*)d_ws;
    float* regular = ws;                               // 16384
    float* QWbuf   = regular + D_M * ALPHA;            // 131072  [h][d][a]
    float* interp  = QWbuf + N_HEADS * D_V * ALPHA;    // 131072  [a][m][h]

    prep_kernel<<<D_M + 128, 256, 0, stream>>>(
        x_ts, t_ts, gm, t2v_w, t2v_phi, wq_w, wq_b, wk_w, regular, QWbuf);
    attn_fused_kernel<<<dim3(2, D_M, N_HEADS), 256, 0, stream>>>(
        x_ts, t_ts, t2v_w, t2v_phi, QWbuf, interp);
    final_kernel<<<ALPHA, 256, 0, stream>>>(
        regular, interp, conv_w, conv_b, proj_w, proj_b,
        g1_w, g1_b, g2_w, g2_b, out);
}

// Round 8
// 105.976 us; speedup vs baseline: 1.1917x; 1.1917x over previous
//
#include <hip/hip_runtime.h>

#define D_M     64
#define L_OBS   256
#define ALPHA   256
#define D_H     256
#define D_V     64
#define N_HEADS 8

// ---------------------------------------------------------------------------
// Kernel 1: prep. Blocks 0..63: per-row imputation (wave-scan cummax).
// Blocks 64..191: per-(h, 16-a-chunk) fold: Qa = theta_a.wq^T + wq_b,
// QW[d][a] = Qa.wk[.][d]. (a-constant score terms dropped: softmax shift-inv.)
// ---------------------------------------------------------------------------
__global__ __launch_bounds__(256) void prep_kernel(
    const float* __restrict__ x_ts, const float* __restrict__ t_ts,
    const float* __restrict__ gm,
    const float* __restrict__ t2v_w, const float* __restrict__ t2v_phi,
    const float* __restrict__ wq_w, const float* __restrict__ wq_b,
    const float* __restrict__ wk_w,
    float* __restrict__ regular, float* __restrict__ QWbuf)
{
    const int tid = threadIdx.x;

    __shared__ int   last[ALPHA];
    __shared__ float vals[ALPHA];
    __shared__ int   wtot[4];
    __shared__ __align__(16) float wq_s[D_V][68];
    __shared__ __align__(16) float thA[16][68];
    __shared__ __align__(16) float QaT[16][68];

    if (blockIdx.x < D_M) {
        // ---------------- imputation ----------------
        const int m  = blockIdx.x;
        const int l  = tid;
        const int wv = tid >> 6;
        const int ln = tid & 63;
        last[l] = -1;
        __syncthreads();
        float x = x_ts[m * L_OBS + l];
        float t = t_ts[m * L_OBS + l];
        bool valid = (x == x) && (t >= 0.0f);
        int idx = (int)t;
        if (valid && idx < ALPHA) atomicMax(&last[idx], l);
        __syncthreads();
        int li = last[l];
        vals[l] = (li >= 0) ? x_ts[m * L_OBS + li] : 0.0f;
        int p = (li >= 0) ? l : -1;
        // wave-level inclusive cummax scan
        #pragma unroll
        for (int s = 1; s < 64; s <<= 1) {
            int q = __shfl_up(p, s);
            if (ln >= s && q > p) p = q;
        }
        if (ln == 63) wtot[wv] = p;
        __syncthreads();   // vals[] and wtot[] visible
        int pre = -1;
        for (int w = 0; w < 4; w++)
            if (w < wv && wtot[w] > pre) pre = wtot[w];
        int lp = (pre > p) ? pre : p;
        regular[m * ALPHA + l] = (lp >= 0) ? vals[lp] : gm[m];
    } else {
        // ---------------- weight fold + QW for 16 a ----------------
        const int pb = blockIdx.x - D_M;   // 0..127
        const int h  = pb >> 4;
        const int a0 = (pb & 15) * 16;

        {
            const float4* w4 = (const float4*)(wq_w + h * D_V * D_V);
            #pragma unroll
            for (int i = 0; i < 4; i++) {
                int f = i * 256 + tid;
                float4 v = w4[f];
                int e = f >> 4, c = (f & 15) * 4;
                *(float4*)&wq_s[e][c] = v;
            }
        }
        {
            int al = tid >> 4, j0 = (tid & 15) * 4;
            float tv = (float)(a0 + al);
            #pragma unroll
            for (int j = 0; j < 4; j++) {
                int d = j0 + j;
                float f = t2v_w[h * D_V + d] * tv + t2v_phi[h * D_V + d];
                thA[al][d] = (d == 0) ? f : __sinf(f);
            }
        }
        __syncthreads();

        // Phase A: QaT[a][e] = thA[a] . wq_s[e] + wq_b[e]
        {
            const int e  = tid >> 2;
            const int ap = tid & 3;
            float accA[4] = {0.f, 0.f, 0.f, 0.f};
            const float4* wrow = (const float4*)&wq_s[e][0];
            #pragma unroll
            for (int j = 0; j < 16; j++) {
                float4 w = wrow[j];
                #pragma unroll
                for (int k = 0; k < 4; k++) {
                    float4 tv = *(const float4*)&thA[ap + 4 * k][j * 4];
                    accA[k] += w.x * tv.x + w.y * tv.y + w.z * tv.z + w.w * tv.w;
                }
            }
            float bq = wq_b[h * D_V + e];
            #pragma unroll
            for (int k = 0; k < 4; k++) QaT[ap + 4 * k][e] = accA[k] + bq;
        }
        __syncthreads();

        // Phase B: QW[d][a] = sum_e QaT[a][e] * wk_w[h][e][d]
        {
            const int d  = tid >> 2;
            const int ap = tid & 3;
            float accB[4] = {0.f, 0.f, 0.f, 0.f};
            #pragma unroll 4
            for (int e4 = 0; e4 < 16; e4++) {
                const float* wkp = &wk_w[(h * D_V + e4 * 4) * D_V + d];
                float w0 = wkp[0];
                float w1 = wkp[D_V];
                float w2 = wkp[2 * D_V];
                float w3 = wkp[3 * D_V];
                #pragma unroll
                for (int k = 0; k < 4; k++) {
                    float4 qv = *(const float4*)&QaT[ap + 4 * k][e4 * 4];
                    accB[k] += qv.x * w0 + qv.y * w1 + qv.z * w2 + qv.w * w3;
                }
            }
            #pragma unroll
            for (int k = 0; k < 4; k++)
                QWbuf[h * D_V * ALPHA + d * ALPHA + a0 + ap + 4 * k] = accB[k];
        }
    }
}

// ---------------------------------------------------------------------------
// Kernel 2: fused mTAND attention, compacted, d-chunked for occupancy.
// Grid (2 ah, 64 m, 8 h) = 1024 blocks (4/CU), 256 thr, LDS ~35 KB ->
// 16 waves/CU (50%). Per 128-l supertile, two 32-d chunks: stage QW chunk
// (16KB, from L2) + theta chunk (16KB, computed) -> 8a x 8l register tile
// (64 acc), 4 ds_read_b128 / 64 FMA, patterns conflict-free (R6-measured 0).
// acc carries across chunks. Lane-local online softmax (exp2 domain), one
// 16-lane merge at the end. Compaction: ballot/popc, tail mask -1e9 (exact).
// ---------------------------------------------------------------------------
__global__ __launch_bounds__(256, 4) void attn_fused_kernel(
    const float* __restrict__ x_ts, const float* __restrict__ t_ts,
    const float* __restrict__ t2v_w, const float* __restrict__ t2v_phi,
    const float* __restrict__ QWbuf, float* __restrict__ interp)
{
    const int ah  = blockIdx.x;          // a-half (128 a)
    const int m   = blockIdx.y;
    const int h   = blockIdx.z;
    const int tid = threadIdx.x;
    const int wv  = tid >> 6;
    const int ln  = tid & 63;
    const int a0  = ah * 128;

    __shared__ __align__(16) float QWs[32 * 128];   // 16 KiB [dchunk][a-a0]
    __shared__ __align__(16) float tht[32 * 128];   // 16 KiB [dchunk][lc]
    __shared__ __align__(16) float xc[L_OBS], tc[L_OBS];
    __shared__ float t2vw_s[D_V], t2vp_s[D_V];
    __shared__ int   cnt_s[4];

    if (tid < D_V)          t2vw_s[tid]       = t2v_w[h * D_V + tid];
    else if (tid < 2 * D_V) t2vp_s[tid - D_V] = t2v_phi[h * D_V + tid - D_V];
    xc[tid] = 0.0f;
    tc[tid] = 0.0f;

    // load obs, ballot-compact
    float x = x_ts[m * L_OBS + tid];
    float t = t_ts[m * L_OBS + tid];
    bool  v = (x == x) && (t >= 0.0f);
    unsigned long long bal = __ballot(v);
    if (ln == 0) cnt_s[wv] = __popcll(bal);
    __syncthreads();
    const int c0 = cnt_s[0], c1 = cnt_s[1], c2 = cnt_s[2], c3 = cnt_s[3];
    const int Lv = c0 + c1 + c2 + c3;
    {
        int base = (wv > 0 ? c0 : 0) + (wv > 1 ? c1 : 0) + (wv > 2 ? c2 : 0);
        unsigned long long lm = (1ull << ln) - 1ull;
        if (v) { int p = base + __popcll(bal & lm); xc[p] = x; tc[p] = t; }
    }
    // scatter made visible by the first __syncthreads() in the dc loop

    const int ta   = tid >> 4;     // 16 groups x 8 a
    const int tl   = tid & 15;     // 16 groups x 8 l
    const int lq   = tid & 127;    // theta fill: l
    const int dgrp = (tid >> 7) * 16;  // theta fill: 16 d rows
    const int nst  = (Lv > 128) ? 2 : 1;
    const float SCALE2 = 0.18033688011112042f;   // 0.125 * log2(e)

    float mrun[8], ssum[8], axs[8];
    #pragma unroll
    for (int i = 0; i < 8; i++) { mrun[i] = -3.0e38f; ssum[i] = 0.f; axs[i] = 0.f; }

    const float4* QWg  = (const float4*)(QWbuf + h * D_V * ALPHA);  // 64 f4/row
    float4*       QWs4 = (float4*)QWs;
    const float4* QW4  = (const float4*)QWs;
    const float4* TH4  = (const float4*)tht;

    for (int st = 0; st < nst; st++) {
        float acc[8][8];
        #pragma unroll
        for (int i = 0; i < 8; i++)
            #pragma unroll
            for (int j = 0; j < 8; j++) acc[i][j] = 0.f;

        for (int dc = 0; dc < 2; dc++) {
            __syncthreads();   // prev chunk's reads done; scatter visible (1st iter)
            // stage QW chunk: rows dc*32..+32, cols a0..a0+128 (1024 f4)
            #pragma unroll
            for (int k = 0; k < 4; k++) {
                int f  = k * 256 + tid;
                int dr = f >> 5, cc = f & 31;
                QWs4[f] = QWg[(dc * 32 + dr) * 64 + (a0 >> 2) + cc];
            }
            // theta chunk: 16 sins per thread
            {
                float tval = tc[st * 128 + lq];
                #pragma unroll
                for (int dd = 0; dd < 16; dd++) {
                    int d  = dgrp + dd;
                    int dg = dc * 32 + d;
                    float f = t2vw_s[dg] * tval + t2vp_s[dg];
                    tht[d * 128 + lq] = (dg == 0) ? f : __sinf(f);
                }
            }
            __syncthreads();
            // compute: 8a x 8l over 32 d
            #pragma unroll 4
            for (int d = 0; d < 32; d++) {
                float4 q0 = QW4[d * 32 + ta * 2];
                float4 q1 = QW4[d * 32 + ta * 2 + 1];
                float4 t0 = TH4[d * 32 + tl * 2];
                float4 t1 = TH4[d * 32 + tl * 2 + 1];
                float qa[8] = {q0.x, q0.y, q0.z, q0.w, q1.x, q1.y, q1.z, q1.w};
                float tb[8] = {t0.x, t0.y, t0.z, t0.w, t1.x, t1.y, t1.z, t1.w};
                #pragma unroll
                for (int i = 0; i < 8; i++)
                    #pragma unroll
                    for (int j = 0; j < 8; j++)
                        acc[i][j] = fmaf(qa[i], tb[j], acc[i][j]);
            }
        }
        // ---- lane-local online softmax update ----
        int lb = st * 128 + tl * 8;
        float4 x0 = *(const float4*)&xc[lb];
        float4 x1 = *(const float4*)&xc[lb + 4];
        float xv[8] = {x0.x, x0.y, x0.z, x0.w, x1.x, x1.y, x1.z, x1.w};
        float mk[8];
        #pragma unroll
        for (int j = 0; j < 8; j++) mk[j] = (lb + j < Lv) ? 0.0f : -1.0e9f;
        #pragma unroll
        for (int i = 0; i < 8; i++) {
            float s[8];
            #pragma unroll
            for (int j = 0; j < 8; j++) s[j] = fmaf(acc[i][j], SCALE2, mk[j]);
            float tmax = s[0];
            #pragma unroll
            for (int j = 1; j < 8; j++) tmax = fmaxf(tmax, s[j]);
            float mnew = fmaxf(mrun[i], tmax);
            float scl = __builtin_amdgcn_exp2f(mrun[i] - mnew);
            float ps = 0.f, px = 0.f;
            #pragma unroll
            for (int j = 0; j < 8; j++) {
                float pv = __builtin_amdgcn_exp2f(s[j] - mnew);
                ps += pv;
                px = fmaf(pv, xv[j], px);
            }
            ssum[i] = fmaf(ssum[i], scl, ps);
            axs[i]  = fmaf(axs[i],  scl, px);
            mrun[i] = mnew;
        }
    }

    // ---- merge across the 16 tl lanes, write interp [a][m][h] ----
    #pragma unroll
    for (int i = 0; i < 8; i++) {
        float m0 = mrun[i];
        m0 = fmaxf(m0, __shfl_xor(m0, 1));
        m0 = fmaxf(m0, __shfl_xor(m0, 2));
        m0 = fmaxf(m0, __shfl_xor(m0, 4));
        m0 = fmaxf(m0, __shfl_xor(m0, 8));
        float f = __builtin_amdgcn_exp2f(mrun[i] - m0);
        float S = ssum[i] * f;
        float A = axs[i] * f;
        S += __shfl_xor(S, 1); A += __shfl_xor(A, 1);
        S += __shfl_xor(S, 2); A += __shfl_xor(A, 2);
        S += __shfl_xor(S, 4); A += __shfl_xor(A, 4);
        S += __shfl_xor(S, 8); A += __shfl_xor(A, 8);
        if (tl == 0)
            interp[(a0 + ta * 8 + i) * (D_M * N_HEADS) + m * N_HEADS + h] = A / S;
    }
}

// ---------------------------------------------------------------------------
// Kernel 3: fused e_imp + e_attn + gate MLP + output. Block per a, 256 thr.
// ---------------------------------------------------------------------------
__global__ __launch_bounds__(256) void final_kernel(
    const float* __restrict__ regular, const float* __restrict__ interp,
    const float* __restrict__ conv_w, const float* __restrict__ conv_b,
    const float* __restrict__ proj_w, const float* __restrict__ proj_b,
    const float* __restrict__ g1_w, const float* __restrict__ g1_b,
    const float* __restrict__ g2_w, const float* __restrict__ g2_b,
    float* __restrict__ out)
{
    const int a = blockIdx.x;
    const int tid = threadIdx.x;
    __shared__ float isum_s[N_HEADS];
    __shared__ __align__(16) float col[D_M];
    __shared__ __align__(16) float c_s[2 * D_H];
    __shared__ __align__(16) float h_s[D_H];

    if (tid < 64) {
        const float4* i4 = (const float4*)&interp[a * (D_M * N_HEADS) + tid * 8];
        float4 v0 = i4[0], v1 = i4[1];
        float v[8] = {v0.x, v0.y, v0.z, v0.w, v1.x, v1.y, v1.z, v1.w};
        #pragma unroll
        for (int s = 1; s < 64; s <<= 1) {
            #pragma unroll
            for (int j = 0; j < 8; j++) v[j] += __shfl_xor(v[j], s);
        }
        if (tid == 0) {
            #pragma unroll
            for (int j = 0; j < 8; j++) isum_s[j] = v[j];
        }
    } else if (tid < 128) {
        col[tid - 64] = regular[(tid - 64) * ALPHA + a];
    }
    __syncthreads();

    float vattn;
    {
        const float4* p4 = (const float4*)&proj_w[tid * N_HEADS];
        float4 v0 = p4[0], v1 = p4[1];
        float sum = v0.x * isum_s[0] + v0.y * isum_s[1] + v0.z * isum_s[2]
                  + v0.w * isum_s[3] + v1.x * isum_s[4] + v1.y * isum_s[5]
                  + v1.z * isum_s[6] + v1.w * isum_s[7];
        vattn = proj_b[tid] + sum * (1.0f / 64.0f);
    }
    float vimp;
    {
        const float4* row = (const float4*)&conv_w[tid * D_M];
        const float4* c4  = (const float4*)col;
        float s0 = 0.f, s1 = 0.f, s2 = 0.f, s3 = 0.f;
        #pragma unroll
        for (int i = 0; i < D_M / 4; i++) {
            float4 r = row[i]; float4 c = c4[i];
            s0 += r.x * c.x; s1 += r.y * c.y; s2 += r.z * c.z; s3 += r.w * c.w;
        }
        vimp = conv_b[tid] + ((s0 + s1) + (s2 + s3));
    }
    c_s[tid]       = vimp;
    c_s[D_H + tid] = vattn;
    __syncthreads();

    {
        const float4* grow = (const float4*)&g1_w[tid * 2 * D_H];
        const float4* c4 = (const float4*)c_s;
        float s0 = 0.f, s1 = 0.f, s2 = 0.f, s3 = 0.f;
        #pragma unroll 8
        for (int i = 0; i < (2 * D_H) / 4; i++) {
            float4 g = grow[i]; float4 c = c4[i];
            s0 += g.x * c.x; s1 += g.y * c.y; s2 += g.z * c.z; s3 += g.w * c.w;
        }
        float hid = g1_b[tid] + ((s0 + s1) + (s2 + s3));
        h_s[tid] = fmaxf(hid, 0.0f);
    }
    __syncthreads();
    {
        const float4* grow = (const float4*)&g2_w[tid * D_H];
        const float4* h4 = (const float4*)h_s;
        float s0 = 0.f, s1 = 0.f, s2 = 0.f, s3 = 0.f;
        #pragma unroll 8
        for (int i = 0; i < D_H / 4; i++) {
            float4 g = grow[i]; float4 hh = h4[i];
            s0 += g.x * hh.x; s1 += g.y * hh.y; s2 += g.z * hh.z; s3 += g.w * hh.w;
        }
        float z = g2_b[tid] + ((s0 + s1) + (s2 + s3));
        float gate = 1.0f / (1.0f + __expf(-z));
        out[a * D_H + tid] = gate * vimp + (1.0f - gate) * vattn;
    }
}

// ---------------------------------------------------------------------------
extern "C" void kernel_launch(void* const* d_in, const int* in_sizes, int n_in,
                              void* d_out, int out_size, void* d_ws, size_t ws_size,
                              hipStream_t stream)
{
    (void)in_sizes; (void)n_in; (void)out_size; (void)ws_size;

    const float* x_ts    = (const float*)d_in[0];
    const float* t_ts    = (const float*)d_in[1];
    const float* gm      = (const float*)d_in[2];
    const float* conv_w  = (const float*)d_in[3];
    const float* conv_b  = (const float*)d_in[4];
    const float* t2v_w   = (const float*)d_in[5];
    const float* t2v_phi = (const float*)d_in[6];
    const float* wq_w    = (const float*)d_in[7];
    const float* wq_b    = (const float*)d_in[8];
    const float* wk_w    = (const float*)d_in[9];
    const float* proj_w  = (const float*)d_in[11];
    const float* proj_b  = (const float*)d_in[12];
    const float* g1_w    = (const float*)d_in[13];
    const float* g1_b    = (const float*)d_in[14];
    const float* g2_w    = (const float*)d_in[15];
    const float* g2_b    = (const float*)d_in[16];

    float* out = (float*)d_out;

    float* ws      = (float*)d_ws;
    float* regular = ws;                               // 16384
    float* QWbuf   = regular + D_M * ALPHA;            // 131072  [h][d][a]
    float* interp  = QWbuf + N_HEADS * D_V * ALPHA;    // 131072  [a][m][h]

    prep_kernel<<<D_M + 128, 256, 0, stream>>>(
        x_ts, t_ts, gm, t2v_w, t2v_phi, wq_w, wq_b, wk_w, regular, QWbuf);
    attn_fused_kernel<<<dim3(2, D_M, N_HEADS), 256, 0, stream>>>(
        x_ts, t_ts, t2v_w, t2v_phi, QWbuf, interp);
    final_kernel<<<ALPHA, 256, 0, stream>>>(
        regular, interp, conv_w, conv_b, proj_w, proj_b,
        g1_w, g1_b, g2_w, g2_b, out);
}

// Round 9
// 96.659 us; speedup vs baseline: 1.3065x; 1.0964x over previous
//
#include <hip/hip_runtime.h>

#define D_M     64
#define L_OBS   256
#define ALPHA   256
#define D_H     256
#define D_V     64
#define N_HEADS 8

// ---------------------------------------------------------------------------
// Kernel 1: prep. Blocks 0..63: per-row imputation (wave-scan cummax).
// Blocks 64..191: per-(h, 16-a-chunk) fold: Qa = theta_a.wq^T + wq_b,
// QW[d][a] = Qa.wk[.][d]. (a-constant score terms dropped: softmax shift-inv.)
// ---------------------------------------------------------------------------
__global__ __launch_bounds__(256) void prep_kernel(
    const float* __restrict__ x_ts, const float* __restrict__ t_ts,
    const float* __restrict__ gm,
    const float* __restrict__ t2v_w, const float* __restrict__ t2v_phi,
    const float* __restrict__ wq_w, const float* __restrict__ wq_b,
    const float* __restrict__ wk_w,
    float* __restrict__ regular, float* __restrict__ QWbuf)
{
    const int tid = threadIdx.x;

    __shared__ int   last[ALPHA];
    __shared__ float vals[ALPHA];
    __shared__ int   wtot[4];
    __shared__ __align__(16) float wq_s[D_V][68];
    __shared__ __align__(16) float thA[16][68];
    __shared__ __align__(16) float QaT[16][68];

    if (blockIdx.x < D_M) {
        // ---------------- imputation ----------------
        const int m  = blockIdx.x;
        const int l  = tid;
        const int wv = tid >> 6;
        const int ln = tid & 63;
        last[l] = -1;
        __syncthreads();
        float x = x_ts[m * L_OBS + l];
        float t = t_ts[m * L_OBS + l];
        bool valid = (x == x) && (t >= 0.0f);
        int idx = (int)t;
        if (valid && idx < ALPHA) atomicMax(&last[idx], l);
        __syncthreads();
        int li = last[l];
        vals[l] = (li >= 0) ? x_ts[m * L_OBS + li] : 0.0f;
        int p = (li >= 0) ? l : -1;
        // wave-level inclusive cummax scan
        #pragma unroll
        for (int s = 1; s < 64; s <<= 1) {
            int q = __shfl_up(p, s);
            if (ln >= s && q > p) p = q;
        }
        if (ln == 63) wtot[wv] = p;
        __syncthreads();   // vals[] and wtot[] visible
        int pre = -1;
        for (int w = 0; w < 4; w++)
            if (w < wv && wtot[w] > pre) pre = wtot[w];
        int lp = (pre > p) ? pre : p;
        regular[m * ALPHA + l] = (lp >= 0) ? vals[lp] : gm[m];
    } else {
        // ---------------- weight fold + QW for 16 a ----------------
        const int pb = blockIdx.x - D_M;   // 0..127
        const int h  = pb >> 4;
        const int a0 = (pb & 15) * 16;

        {
            const float4* w4 = (const float4*)(wq_w + h * D_V * D_V);
            #pragma unroll
            for (int i = 0; i < 4; i++) {
                int f = i * 256 + tid;
                float4 v = w4[f];
                int e = f >> 4, c = (f & 15) * 4;
                *(float4*)&wq_s[e][c] = v;
            }
        }
        {
            int al = tid >> 4, j0 = (tid & 15) * 4;
            float tv = (float)(a0 + al);
            #pragma unroll
            for (int j = 0; j < 4; j++) {
                int d = j0 + j;
                float f = t2v_w[h * D_V + d] * tv + t2v_phi[h * D_V + d];
                thA[al][d] = (d == 0) ? f : __sinf(f);
            }
        }
        __syncthreads();

        // Phase A: QaT[a][e] = thA[a] . wq_s[e] + wq_b[e]
        {
            const int e  = tid >> 2;
            const int ap = tid & 3;
            float accA[4] = {0.f, 0.f, 0.f, 0.f};
            const float4* wrow = (const float4*)&wq_s[e][0];
            #pragma unroll
            for (int j = 0; j < 16; j++) {
                float4 w = wrow[j];
                #pragma unroll
                for (int k = 0; k < 4; k++) {
                    float4 tv = *(const float4*)&thA[ap + 4 * k][j * 4];
                    accA[k] += w.x * tv.x + w.y * tv.y + w.z * tv.z + w.w * tv.w;
                }
            }
            float bq = wq_b[h * D_V + e];
            #pragma unroll
            for (int k = 0; k < 4; k++) QaT[ap + 4 * k][e] = accA[k] + bq;
        }
        __syncthreads();

        // Phase B: QW[d][a] = sum_e QaT[a][e] * wk_w[h][e][d]
        {
            const int d  = tid >> 2;
            const int ap = tid & 3;
            float accB[4] = {0.f, 0.f, 0.f, 0.f};
            #pragma unroll 4
            for (int e4 = 0; e4 < 16; e4++) {
                const float* wkp = &wk_w[(h * D_V + e4 * 4) * D_V + d];
                float w0 = wkp[0];
                float w1 = wkp[D_V];
                float w2 = wkp[2 * D_V];
                float w3 = wkp[3 * D_V];
                #pragma unroll
                for (int k = 0; k < 4; k++) {
                    float4 qv = *(const float4*)&QaT[ap + 4 * k][e4 * 4];
                    accB[k] += qv.x * w0 + qv.y * w1 + qv.z * w2 + qv.w * w3;
                }
            }
            #pragma unroll
            for (int k = 0; k < 4; k++)
                QWbuf[h * D_V * ALPHA + d * ALPHA + a0 + ap + 4 * k] = accB[k];
        }
    }
}

// ---------------------------------------------------------------------------
// Kernel 2: fused mTAND attention, compacted, d-chunked.
// Grid (2 ah, 64 m, 8 h) = 1024 blocks, 256 thr, LDS ~35 KB -> 4 blocks/CU
// by LDS. NO min-waves launch_bounds hint: R8's (256,4) made the allocator
// target 64 VGPR and spill the 64-float accumulator to scratch (33 MB/launch
// of scratch writes). Plain (256) reproduces R6's no-spill allocation.
// Per 128-l supertile, two 32-d chunks: stage QW chunk (16KB from L2) +
// theta chunk (16KB computed) -> 8a x 8l register tile, 4 ds_read_b128 /
// 64 FMA, conflict-free patterns. acc carries across chunks. Lane-local
// online softmax (exp2 domain); one 16-lane merge at the end.
// ---------------------------------------------------------------------------
__global__ __launch_bounds__(256) void attn_fused_kernel(
    const float* __restrict__ x_ts, const float* __restrict__ t_ts,
    const float* __restrict__ t2v_w, const float* __restrict__ t2v_phi,
    const float* __restrict__ QWbuf, float* __restrict__ interp)
{
    const int ah  = blockIdx.x;          // a-half (128 a)
    const int m   = blockIdx.y;
    const int h   = blockIdx.z;
    const int tid = threadIdx.x;
    const int wv  = tid >> 6;
    const int ln  = tid & 63;
    const int a0  = ah * 128;

    __shared__ __align__(16) float QWs[32 * 128];   // 16 KiB [dchunk][a-a0]
    __shared__ __align__(16) float tht[32 * 128];   // 16 KiB [dchunk][lc]
    __shared__ __align__(16) float xc[L_OBS], tc[L_OBS];
    __shared__ float t2vw_s[D_V], t2vp_s[D_V];
    __shared__ int   cnt_s[4];

    if (tid < D_V)          t2vw_s[tid]       = t2v_w[h * D_V + tid];
    else if (tid < 2 * D_V) t2vp_s[tid - D_V] = t2v_phi[h * D_V + tid - D_V];
    xc[tid] = 0.0f;
    tc[tid] = 0.0f;

    // load obs, ballot-compact
    float x = x_ts[m * L_OBS + tid];
    float t = t_ts[m * L_OBS + tid];
    bool  v = (x == x) && (t >= 0.0f);
    unsigned long long bal = __ballot(v);
    if (ln == 0) cnt_s[wv] = __popcll(bal);
    __syncthreads();
    const int c0 = cnt_s[0], c1 = cnt_s[1], c2 = cnt_s[2], c3 = cnt_s[3];
    const int Lv = c0 + c1 + c2 + c3;
    {
        int base = (wv > 0 ? c0 : 0) + (wv > 1 ? c1 : 0) + (wv > 2 ? c2 : 0);
        unsigned long long lm = (1ull << ln) - 1ull;
        if (v) { int p = base + __popcll(bal & lm); xc[p] = x; tc[p] = t; }
    }
    // scatter made visible by the first __syncthreads() in the dc loop

    const int ta   = tid >> 4;     // 16 groups x 8 a
    const int tl   = tid & 15;     // 16 groups x 8 l
    const int lq   = tid & 127;    // theta fill: l
    const int dgrp = (tid >> 7) * 16;  // theta fill: 16 d rows
    const int nst  = (Lv > 128) ? 2 : 1;
    const float SCALE2 = 0.18033688011112042f;   // 0.125 * log2(e)

    float mrun[8], ssum[8], axs[8];
    #pragma unroll
    for (int i = 0; i < 8; i++) { mrun[i] = -3.0e38f; ssum[i] = 0.f; axs[i] = 0.f; }

    const float4* QWg  = (const float4*)(QWbuf + h * D_V * ALPHA);  // 64 f4/row
    float4*       QWs4 = (float4*)QWs;
    const float4* QW4  = (const float4*)QWs;
    const float4* TH4  = (const float4*)tht;

    for (int st = 0; st < nst; st++) {
        float acc[8][8];
        #pragma unroll
        for (int i = 0; i < 8; i++)
            #pragma unroll
            for (int j = 0; j < 8; j++) acc[i][j] = 0.f;

        for (int dc = 0; dc < 2; dc++) {
            __syncthreads();   // prev chunk's reads done; scatter visible (1st iter)
            // stage QW chunk: rows dc*32..+32, cols a0..a0+128 (1024 f4)
            #pragma unroll
            for (int k = 0; k < 4; k++) {
                int f  = k * 256 + tid;
                int dr = f >> 5, cc = f & 31;
                QWs4[f] = QWg[(dc * 32 + dr) * 64 + (a0 >> 2) + cc];
            }
            // theta chunk: 16 sins per thread
            {
                float tval = tc[st * 128 + lq];
                #pragma unroll
                for (int dd = 0; dd < 16; dd++) {
                    int d  = dgrp + dd;
                    int dg = dc * 32 + d;
                    float f = t2vw_s[dg] * tval + t2vp_s[dg];
                    tht[d * 128 + lq] = (dg == 0) ? f : __sinf(f);
                }
            }
            __syncthreads();
            // compute: 8a x 8l over 32 d
            #pragma unroll 4
            for (int d = 0; d < 32; d++) {
                float4 q0 = QW4[d * 32 + ta * 2];
                float4 q1 = QW4[d * 32 + ta * 2 + 1];
                float4 t0 = TH4[d * 32 + tl * 2];
                float4 t1 = TH4[d * 32 + tl * 2 + 1];
                float qa[8] = {q0.x, q0.y, q0.z, q0.w, q1.x, q1.y, q1.z, q1.w};
                float tb[8] = {t0.x, t0.y, t0.z, t0.w, t1.x, t1.y, t1.z, t1.w};
                #pragma unroll
                for (int i = 0; i < 8; i++)
                    #pragma unroll
                    for (int j = 0; j < 8; j++)
                        acc[i][j] = fmaf(qa[i], tb[j], acc[i][j]);
            }
        }
        // ---- lane-local online softmax update ----
        int lb = st * 128 + tl * 8;
        float4 x0 = *(const float4*)&xc[lb];
        float4 x1 = *(const float4*)&xc[lb + 4];
        float xv[8] = {x0.x, x0.y, x0.z, x0.w, x1.x, x1.y, x1.z, x1.w};
        float mk[8];
        #pragma unroll
        for (int j = 0; j < 8; j++) mk[j] = (lb + j < Lv) ? 0.0f : -1.0e9f;
        #pragma unroll
        for (int i = 0; i < 8; i++) {
            float s[8];
            #pragma unroll
            for (int j = 0; j < 8; j++) s[j] = fmaf(acc[i][j], SCALE2, mk[j]);
            float tmax = s[0];
            #pragma unroll
            for (int j = 1; j < 8; j++) tmax = fmaxf(tmax, s[j]);
            float mnew = fmaxf(mrun[i], tmax);
            float scl = __builtin_amdgcn_exp2f(mrun[i] - mnew);
            float ps = 0.f, px = 0.f;
            #pragma unroll
            for (int j = 0; j < 8; j++) {
                float pv = __builtin_amdgcn_exp2f(s[j] - mnew);
                ps += pv;
                px = fmaf(pv, xv[j], px);
            }
            ssum[i] = fmaf(ssum[i], scl, ps);
            axs[i]  = fmaf(axs[i],  scl, px);
            mrun[i] = mnew;
        }
    }

    // ---- merge across the 16 tl lanes, write interp [a][m][h] ----
    #pragma unroll
    for (int i = 0; i < 8; i++) {
        float m0 = mrun[i];
        m0 = fmaxf(m0, __shfl_xor(m0, 1));
        m0 = fmaxf(m0, __shfl_xor(m0, 2));
        m0 = fmaxf(m0, __shfl_xor(m0, 4));
        m0 = fmaxf(m0, __shfl_xor(m0, 8));
        float f = __builtin_amdgcn_exp2f(mrun[i] - m0);
        float S = ssum[i] * f;
        float A = axs[i] * f;
        S += __shfl_xor(S, 1); A += __shfl_xor(A, 1);
        S += __shfl_xor(S, 2); A += __shfl_xor(A, 2);
        S += __shfl_xor(S, 4); A += __shfl_xor(A, 4);
        S += __shfl_xor(S, 8); A += __shfl_xor(A, 8);
        if (tl == 0)
            interp[(a0 + ta * 8 + i) * (D_M * N_HEADS) + m * N_HEADS + h] = A / S;
    }
}

// ---------------------------------------------------------------------------
// Kernel 3: fused e_imp + e_attn + gate MLP + output. Block per a, 256 thr.
// ---------------------------------------------------------------------------
__global__ __launch_bounds__(256) void final_kernel(
    const float* __restrict__ regular, const float* __restrict__ interp,
    const float* __restrict__ conv_w, const float* __restrict__ conv_b,
    const float* __restrict__ proj_w, const float* __restrict__ proj_b,
    const float* __restrict__ g1_w, const float* __restrict__ g1_b,
    const float* __restrict__ g2_w, const float* __restrict__ g2_b,
    float* __restrict__ out)
{
    const int a = blockIdx.x;
    const int tid = threadIdx.x;
    __shared__ float isum_s[N_HEADS];
    __shared__ __align__(16) float col[D_M];
    __shared__ __align__(16) float c_s[2 * D_H];
    __shared__ __align__(16) float h_s[D_H];

    if (tid < 64) {
        const float4* i4 = (const float4*)&interp[a * (D_M * N_HEADS) + tid * 8];
        float4 v0 = i4[0], v1 = i4[1];
        float v[8] = {v0.x, v0.y, v0.z, v0.w, v1.x, v1.y, v1.z, v1.w};
        #pragma unroll
        for (int s = 1; s < 64; s <<= 1) {
            #pragma unroll
            for (int j = 0; j < 8; j++) v[j] += __shfl_xor(v[j], s);
        }
        if (tid == 0) {
            #pragma unroll
            for (int j = 0; j < 8; j++) isum_s[j] = v[j];
        }
    } else if (tid < 128) {
        col[tid - 64] = regular[(tid - 64) * ALPHA + a];
    }
    __syncthreads();

    float vattn;
    {
        const float4* p4 = (const float4*)&proj_w[tid * N_HEADS];
        float4 v0 = p4[0], v1 = p4[1];
        float sum = v0.x * isum_s[0] + v0.y * isum_s[1] + v0.z * isum_s[2]
                  + v0.w * isum_s[3] + v1.x * isum_s[4] + v1.y * isum_s[5]
                  + v1.z * isum_s[6] + v1.w * isum_s[7];
        vattn = proj_b[tid] + sum * (1.0f / 64.0f);
    }
    float vimp;
    {
        const float4* row = (const float4*)&conv_w[tid * D_M];
        const float4* c4  = (const float4*)col;
        float s0 = 0.f, s1 = 0.f, s2 = 0.f, s3 = 0.f;
        #pragma unroll
        for (int i = 0; i < D_M / 4; i++) {
            float4 r = row[i]; float4 c = c4[i];
            s0 += r.x * c.x; s1 += r.y * c.y; s2 += r.z * c.z; s3 += r.w * c.w;
        }
        vimp = conv_b[tid] + ((s0 + s1) + (s2 + s3));
    }
    c_s[tid]       = vimp;
    c_s[D_H + tid] = vattn;
    __syncthreads();

    {
        const float4* grow = (const float4*)&g1_w[tid * 2 * D_H];
        const float4* c4 = (const float4*)c_s;
        float s0 = 0.f, s1 = 0.f, s2 = 0.f, s3 = 0.f;
        #pragma unroll 8
        for (int i = 0; i < (2 * D_H) / 4; i++) {
            float4 g = grow[i]; float4 c = c4[i];
            s0 += g.x * c.x; s1 += g.y * c.y; s2 += g.z * c.z; s3 += g.w * c.w;
        }
        float hid = g1_b[tid] + ((s0 + s1) + (s2 + s3));
        h_s[tid] = fmaxf(hid, 0.0f);
    }
    __syncthreads();
    {
        const float4* grow = (const float4*)&g2_w[tid * D_H];
        const float4* h4 = (const float4*)h_s;
        float s0 = 0.f, s1 = 0.f, s2 = 0.f, s3 = 0.f;
        #pragma unroll 8
        for (int i = 0; i < D_H / 4; i++) {
            float4 g = grow[i]; float4 hh = h4[i];
            s0 += g.x * hh.x; s1 += g.y * hh.y; s2 += g.z * hh.z; s3 += g.w * hh.w;
        }
        float z = g2_b[tid] + ((s0 + s1) + (s2 + s3));
        float gate = 1.0f / (1.0f + __expf(-z));
        out[a * D_H + tid] = gate * vimp + (1.0f - gate) * vattn;
    }
}

// ---------------------------------------------------------------------------
extern "C" void kernel_launch(void* const* d_in, const int* in_sizes, int n_in,
                              void* d_out, int out_size, void* d_ws, size_t ws_size,
                              hipStream_t stream)
{
    (void)in_sizes; (void)n_in; (void)out_size; (void)ws_size;

    const float* x_ts    = (const float*)d_in[0];
    const float* t_ts    = (const float*)d_in[1];
    const float* gm      = (const float*)d_in[2];
    const float* conv_w  = (const float*)d_in[3];
    const float* conv_b  = (const float*)d_in[4];
    const float* t2v_w   = (const float*)d_in[5];
    const float* t2v_phi = (const float*)d_in[6];
    const float* wq_w    = (const float*)d_in[7];
    const float* wq_b    = (const float*)d_in[8];
    const float* wk_w    = (const float*)d_in[9];
    const float* proj_w  = (const float*)d_in[11];
    const float* proj_b  = (const float*)d_in[12];
    const float* g1_w    = (const float*)d_in[13];
    const float* g1_b    = (const float*)d_in[14];
    const float* g2_w    = (const float*)d_in[15];
    const float* g2_b    = (const float*)d_in[16];

    float* out = (float*)d_out;

    float* ws      = (float*)d_ws;
    float* regular = ws;                               // 16384
    float* QWbuf   = regular + D_M * ALPHA;            // 131072  [h][d][a]
    float* interp  = QWbuf + N_HEADS * D_V * ALPHA;    // 131072  [a][m][h]

    prep_kernel<<<D_M + 128, 256, 0, stream>>>(
        x_ts, t_ts, gm, t2v_w, t2v_phi, wq_w, wq_b, wk_w, regular, QWbuf);
    attn_fused_kernel<<<dim3(2, D_M, N_HEADS), 256, 0, stream>>>(
        x_ts, t_ts, t2v_w, t2v_phi, QWbuf, interp);
    final_kernel<<<ALPHA, 256, 0, stream>>>(
        regular, interp, conv_w, conv_b, proj_w, proj_b,
        g1_w, g1_b, g2_w, g2_b, out);
}

// Round 10
// 95.670 us; speedup vs baseline: 1.3201x; 1.0103x over previous
//
#include <hip/hip_runtime.h>

#define D_M     64
#define L_OBS   256
#define ALPHA   256
#define D_H     256
#define D_V     64
#define N_HEADS 8

// ---------------------------------------------------------------------------
// Kernel 1: prep. Blocks 0..63: per-row imputation (wave-scan cummax).
// Blocks 64..191: per-(h, 16-a-chunk) fold: Qa = theta_a.wq^T + wq_b,
// QW[d][a] = Qa.wk[.][d]. (a-constant score terms dropped: softmax shift-inv.)
// ---------------------------------------------------------------------------
__global__ __launch_bounds__(256) void prep_kernel(
    const float* __restrict__ x_ts, const float* __restrict__ t_ts,
    const float* __restrict__ gm,
    const float* __restrict__ t2v_w, const float* __restrict__ t2v_phi,
    const float* __restrict__ wq_w, const float* __restrict__ wq_b,
    const float* __restrict__ wk_w,
    float* __restrict__ regular, float* __restrict__ QWbuf)
{
    const int tid = threadIdx.x;

    __shared__ int   last[ALPHA];
    __shared__ float vals[ALPHA];
    __shared__ int   wtot[4];
    __shared__ __align__(16) float wq_s[D_V][68];
    __shared__ __align__(16) float thA[16][68];
    __shared__ __align__(16) float QaT[16][68];

    if (blockIdx.x < D_M) {
        // ---------------- imputation ----------------
        const int m  = blockIdx.x;
        const int l  = tid;
        const int wv = tid >> 6;
        const int ln = tid & 63;
        last[l] = -1;
        __syncthreads();
        float x = x_ts[m * L_OBS + l];
        float t = t_ts[m * L_OBS + l];
        bool valid = (x == x) && (t >= 0.0f);
        int idx = (int)t;
        if (valid && idx < ALPHA) atomicMax(&last[idx], l);
        __syncthreads();
        int li = last[l];
        vals[l] = (li >= 0) ? x_ts[m * L_OBS + li] : 0.0f;
        int p = (li >= 0) ? l : -1;
        // wave-level inclusive cummax scan
        #pragma unroll
        for (int s = 1; s < 64; s <<= 1) {
            int q = __shfl_up(p, s);
            if (ln >= s && q > p) p = q;
        }
        if (ln == 63) wtot[wv] = p;
        __syncthreads();   // vals[] and wtot[] visible
        int pre = -1;
        for (int w = 0; w < 4; w++)
            if (w < wv && wtot[w] > pre) pre = wtot[w];
        int lp = (pre > p) ? pre : p;
        regular[m * ALPHA + l] = (lp >= 0) ? vals[lp] : gm[m];
    } else {
        // ---------------- weight fold + QW for 16 a ----------------
        const int pb = blockIdx.x - D_M;   // 0..127
        const int h  = pb >> 4;
        const int a0 = (pb & 15) * 16;

        {
            const float4* w4 = (const float4*)(wq_w + h * D_V * D_V);
            #pragma unroll
            for (int i = 0; i < 4; i++) {
                int f = i * 256 + tid;
                float4 v = w4[f];
                int e = f >> 4, c = (f & 15) * 4;
                *(float4*)&wq_s[e][c] = v;
            }
        }
        {
            int al = tid >> 4, j0 = (tid & 15) * 4;
            float tv = (float)(a0 + al);
            #pragma unroll
            for (int j = 0; j < 4; j++) {
                int d = j0 + j;
                float f = t2v_w[h * D_V + d] * tv + t2v_phi[h * D_V + d];
                thA[al][d] = (d == 0) ? f : __sinf(f);
            }
        }
        __syncthreads();

        // Phase A: QaT[a][e] = thA[a] . wq_s[e] + wq_b[e]
        {
            const int e  = tid >> 2;
            const int ap = tid & 3;
            float accA[4] = {0.f, 0.f, 0.f, 0.f};
            const float4* wrow = (const float4*)&wq_s[e][0];
            #pragma unroll
            for (int j = 0; j < 16; j++) {
                float4 w = wrow[j];
                #pragma unroll
                for (int k = 0; k < 4; k++) {
                    float4 tv = *(const float4*)&thA[ap + 4 * k][j * 4];
                    accA[k] += w.x * tv.x + w.y * tv.y + w.z * tv.z + w.w * tv.w;
                }
            }
            float bq = wq_b[h * D_V + e];
            #pragma unroll
            for (int k = 0; k < 4; k++) QaT[ap + 4 * k][e] = accA[k] + bq;
        }
        __syncthreads();

        // Phase B: QW[d][a] = sum_e QaT[a][e] * wk_w[h][e][d]
        {
            const int d  = tid >> 2;
            const int ap = tid & 3;
            float accB[4] = {0.f, 0.f, 0.f, 0.f};
            #pragma unroll 4
            for (int e4 = 0; e4 < 16; e4++) {
                const float* wkp = &wk_w[(h * D_V + e4 * 4) * D_V + d];
                float w0 = wkp[0];
                float w1 = wkp[D_V];
                float w2 = wkp[2 * D_V];
                float w3 = wkp[3 * D_V];
                #pragma unroll
                for (int k = 0; k < 4; k++) {
                    float4 qv = *(const float4*)&QaT[ap + 4 * k][e4 * 4];
                    accB[k] += qv.x * w0 + qv.y * w1 + qv.z * w2 + qv.w * w3;
                }
            }
            #pragma unroll
            for (int k = 0; k < 4; k++)
                QWbuf[h * D_V * ALPHA + d * ALPHA + a0 + ap + 4 * k] = accB[k];
        }
    }
}

// ---------------------------------------------------------------------------
// Kernel 2: fused mTAND attention, compacted, QW-from-VMEM.
// Grid (2 ah, 64 m, 8 h) = 1024 blocks, 256 thr.
// LDS holds ONLY theta [64d][128l] (32 KB) + obs (~3 KB): QW is read directly
// from global (L2-resident; 16-lane broadcast, 4 distinct addrs/wave) on the
// VMEM pipe, halving LDS issue. Theta reads are STRIDED: tl in [0,16), reads
// TH4[d*32+tl] and TH4[d*32+16+tl] -> 16 addrs over 8 start banks = 2-way
// (free). QW broadcast groups: ta = tid>>4 -> 4 addrs/wave (banks n/a, VMEM).
// Per thread: 8a x (4+4 strided) l, 64 acc (proven no-fission size).
// 2 barriers per 128-l supertile. Lane-local exp2 softmax; 16-lane merge.
// NO min-waves hint (R8 lesson: it forces a 64-VGPR target and spills).
// ---------------------------------------------------------------------------
__global__ __launch_bounds__(256) void attn_fused_kernel(
    const float* __restrict__ x_ts, const float* __restrict__ t_ts,
    const float* __restrict__ t2v_w, const float* __restrict__ t2v_phi,
    const float* __restrict__ QWbuf, float* __restrict__ interp)
{
    const int ah  = blockIdx.x;          // a-half (128 a)
    const int m   = blockIdx.y;
    const int h   = blockIdx.z;
    const int tid = threadIdx.x;
    const int wv  = tid >> 6;
    const int ln  = tid & 63;
    const int a0  = ah * 128;

    __shared__ __align__(16) float tht[D_V * 128];   // 32 KiB [d][lc]
    __shared__ __align__(16) float xc[L_OBS], tc[L_OBS];
    __shared__ float t2vw_s[D_V], t2vp_s[D_V];
    __shared__ int   cnt_s[4];

    if (tid < D_V)          t2vw_s[tid]       = t2v_w[h * D_V + tid];
    else if (tid < 2 * D_V) t2vp_s[tid - D_V] = t2v_phi[h * D_V + tid - D_V];
    xc[tid] = 0.0f;
    tc[tid] = 0.0f;

    // load obs, ballot-compact
    float x = x_ts[m * L_OBS + tid];
    float t = t_ts[m * L_OBS + tid];
    bool  v = (x == x) && (t >= 0.0f);
    unsigned long long bal = __ballot(v);
    if (ln == 0) cnt_s[wv] = __popcll(bal);
    __syncthreads();
    const int c0 = cnt_s[0], c1 = cnt_s[1], c2 = cnt_s[2], c3 = cnt_s[3];
    const int Lv = c0 + c1 + c2 + c3;
    {
        int base = (wv > 0 ? c0 : 0) + (wv > 1 ? c1 : 0) + (wv > 2 ? c2 : 0);
        unsigned long long lm = (1ull << ln) - 1ull;
        if (v) { int p = base + __popcll(bal & lm); xc[p] = x; tc[p] = t; }
    }
    __syncthreads();   // compacted xc/tc visible to all

    const int ta   = tid >> 4;          // 16 groups x 8 a  (VMEM broadcast)
    const int tl   = tid & 15;          // 16 groups x 8 l  (strided LDS)
    const int lq   = tid & 127;         // theta fill: column
    const int dgrp = (tid >> 7) * 32;   // theta fill: 32 d rows
    const int nst  = (Lv > 128) ? 2 : 1;
    const float SCALE2 = 0.18033688011112042f;   // 0.125 * log2(e)

    float mrun[8], ssum[8], axs[8];
    #pragma unroll
    for (int i = 0; i < 8; i++) { mrun[i] = -3.0e38f; ssum[i] = 0.f; axs[i] = 0.f; }

    const float4* QWg4 = (const float4*)(QWbuf + h * D_V * ALPHA)
                         + (a0 >> 2) + ta * 2;     // + d*64 per row
    const float4* TH4  = (const float4*)tht;
    const float4* XS4  = (const float4*)xc;

    for (int st = 0; st < nst; st++) {
        // ---- fill theta [64 d][128 l] (32 sins/thread) ----
        {
            float tval = tc[st * 128 + lq];
            #pragma unroll 8
            for (int dd = 0; dd < 32; dd++) {
                int d = dgrp + dd;
                float f = t2vw_s[d] * tval + t2vp_s[d];
                tht[d * 128 + lq] = (d == 0) ? f : __sinf(f);
            }
        }
        __syncthreads();
        // ---- compute: 8a x 8l over 64 d; QW from global, theta from LDS ----
        float acc[8][8];
        #pragma unroll
        for (int i = 0; i < 8; i++)
            #pragma unroll
            for (int j = 0; j < 8; j++) acc[i][j] = 0.f;
        #pragma unroll 2
        for (int d = 0; d < D_V; d++) {
            float4 q0 = QWg4[d * 64];
            float4 q1 = QWg4[d * 64 + 1];
            float4 t0 = TH4[d * 32 + tl];        // l = tl*4 .. +3
            float4 t1 = TH4[d * 32 + 16 + tl];   // l = 64+tl*4 .. +3
            float qa[8] = {q0.x, q0.y, q0.z, q0.w, q1.x, q1.y, q1.z, q1.w};
            float tb[8] = {t0.x, t0.y, t0.z, t0.w, t1.x, t1.y, t1.z, t1.w};
            #pragma unroll
            for (int i = 0; i < 8; i++)
                #pragma unroll
                for (int j = 0; j < 8; j++)
                    acc[i][j] = fmaf(qa[i], tb[j], acc[i][j]);
        }
        // ---- lane-local online softmax update (strided l bookkeeping) ----
        int lbA = st * 128 + tl * 4;        // acc[.][0..3]
        int lbB = lbA + 64;                 // acc[.][4..7]
        float4 xA = XS4[st * 32 + tl];
        float4 xB = XS4[st * 32 + 16 + tl];
        float xv[8] = {xA.x, xA.y, xA.z, xA.w, xB.x, xB.y, xB.z, xB.w};
        float mk[8];
        #pragma unroll
        for (int j = 0; j < 4; j++) {
            mk[j]     = (lbA + j < Lv) ? 0.0f : -1.0e9f;
            mk[4 + j] = (lbB + j < Lv) ? 0.0f : -1.0e9f;
        }
        #pragma unroll
        for (int i = 0; i < 8; i++) {
            float s[8];
            #pragma unroll
            for (int j = 0; j < 8; j++) s[j] = fmaf(acc[i][j], SCALE2, mk[j]);
            float tmax = s[0];
            #pragma unroll
            for (int j = 1; j < 8; j++) tmax = fmaxf(tmax, s[j]);
            float mnew = fmaxf(mrun[i], tmax);
            float scl = __builtin_amdgcn_exp2f(mrun[i] - mnew);
            float ps = 0.f, px = 0.f;
            #pragma unroll
            for (int j = 0; j < 8; j++) {
                float pv = __builtin_amdgcn_exp2f(s[j] - mnew);
                ps += pv;
                px = fmaf(pv, xv[j], px);
            }
            ssum[i] = fmaf(ssum[i], scl, ps);
            axs[i]  = fmaf(axs[i],  scl, px);
            mrun[i] = mnew;
        }
        if (st + 1 < nst) __syncthreads();  // tht overwrite guard
    }

    // ---- merge across the 16 tl lanes, write interp [a][m][h] ----
    #pragma unroll
    for (int i = 0; i < 8; i++) {
        float m0 = mrun[i];
        m0 = fmaxf(m0, __shfl_xor(m0, 1));
        m0 = fmaxf(m0, __shfl_xor(m0, 2));
        m0 = fmaxf(m0, __shfl_xor(m0, 4));
        m0 = fmaxf(m0, __shfl_xor(m0, 8));
        float f = __builtin_amdgcn_exp2f(mrun[i] - m0);
        float S = ssum[i] * f;
        float A = axs[i] * f;
        S += __shfl_xor(S, 1); A += __shfl_xor(A, 1);
        S += __shfl_xor(S, 2); A += __shfl_xor(A, 2);
        S += __shfl_xor(S, 4); A += __shfl_xor(A, 4);
        S += __shfl_xor(S, 8); A += __shfl_xor(A, 8);
        if (tl == 0)
            interp[(a0 + ta * 8 + i) * (D_M * N_HEADS) + m * N_HEADS + h] = A / S;
    }
}

// ---------------------------------------------------------------------------
// Kernel 3: fused e_imp + e_attn + gate MLP + output. Block per a, 256 thr.
// ---------------------------------------------------------------------------
__global__ __launch_bounds__(256) void final_kernel(
    const float* __restrict__ regular, const float* __restrict__ interp,
    const float* __restrict__ conv_w, const float* __restrict__ conv_b,
    const float* __restrict__ proj_w, const float* __restrict__ proj_b,
    const float* __restrict__ g1_w, const float* __restrict__ g1_b,
    const float* __restrict__ g2_w, const float* __restrict__ g2_b,
    float* __restrict__ out)
{
    const int a = blockIdx.x;
    const int tid = threadIdx.x;
    __shared__ float isum_s[N_HEADS];
    __shared__ __align__(16) float col[D_M];
    __shared__ __align__(16) float c_s[2 * D_H];
    __shared__ __align__(16) float h_s[D_H];

    if (tid < 64) {
        const float4* i4 = (const float4*)&interp[a * (D_M * N_HEADS) + tid * 8];
        float4 v0 = i4[0], v1 = i4[1];
        float v[8] = {v0.x, v0.y, v0.z, v0.w, v1.x, v1.y, v1.z, v1.w};
        #pragma unroll
        for (int s = 1; s < 64; s <<= 1) {
            #pragma unroll
            for (int j = 0; j < 8; j++) v[j] += __shfl_xor(v[j], s);
        }
        if (tid == 0) {
            #pragma unroll
            for (int j = 0; j < 8; j++) isum_s[j] = v[j];
        }
    } else if (tid < 128) {
        col[tid - 64] = regular[(tid - 64) * ALPHA + a];
    }
    __syncthreads();

    float vattn;
    {
        const float4* p4 = (const float4*)&proj_w[tid * N_HEADS];
        float4 v0 = p4[0], v1 = p4[1];
        float sum = v0.x * isum_s[0] + v0.y * isum_s[1] + v0.z * isum_s[2]
                  + v0.w * isum_s[3] + v1.x * isum_s[4] + v1.y * isum_s[5]
                  + v1.z * isum_s[6] + v1.w * isum_s[7];
        vattn = proj_b[tid] + sum * (1.0f / 64.0f);
    }
    float vimp;
    {
        const float4* row = (const float4*)&conv_w[tid * D_M];
        const float4* c4  = (const float4*)col;
        float s0 = 0.f, s1 = 0.f, s2 = 0.f, s3 = 0.f;
        #pragma unroll
        for (int i = 0; i < D_M / 4; i++) {
            float4 r = row[i]; float4 c = c4[i];
            s0 += r.x * c.x; s1 += r.y * c.y; s2 += r.z * c.z; s3 += r.w * c.w;
        }
        vimp = conv_b[tid] + ((s0 + s1) + (s2 + s3));
    }
    c_s[tid]       = vimp;
    c_s[D_H + tid] = vattn;
    __syncthreads();

    {
        const float4* grow = (const float4*)&g1_w[tid * 2 * D_H];
        const float4* c4 = (const float4*)c_s;
        float s0 = 0.f, s1 = 0.f, s2 = 0.f, s3 = 0.f;
        #pragma unroll 8
        for (int i = 0; i < (2 * D_H) / 4; i++) {
            float4 g = grow[i]; float4 c = c4[i];
            s0 += g.x * c.x; s1 += g.y * c.y; s2 += g.z * c.z; s3 += g.w * c.w;
        }
        float hid = g1_b[tid] + ((s0 + s1) + (s2 + s3));
        h_s[tid] = fmaxf(hid, 0.0f);
    }
    __syncthreads();
    {
        const float4* grow = (const float4*)&g2_w[tid * D_H];
        const float4* h4 = (const float4*)h_s;
        float s0 = 0.f, s1 = 0.f, s2 = 0.f, s3 = 0.f;
        #pragma unroll 8
        for (int i = 0; i < D_H / 4; i++) {
            float4 g = grow[i]; float4 hh = h4[i];
            s0 += g.x * hh.x; s1 += g.y * hh.y; s2 += g.z * hh.z; s3 += g.w * hh.w;
        }
        float z = g2_b[tid] + ((s0 + s1) + (s2 + s3));
        float gate = 1.0f / (1.0f + __expf(-z));
        out[a * D_H + tid] = gate * vimp + (1.0f - gate) * vattn;
    }
}

// ---------------------------------------------------------------------------
extern "C" void kernel_launch(void* const* d_in, const int* in_sizes, int n_in,
                              void* d_out, int out_size, void* d_ws, size_t ws_size,
                              hipStream_t stream)
{
    (void)in_sizes; (void)n_in; (void)out_size; (void)ws_size;

    const float* x_ts    = (const float*)d_in[0];
    const float* t_ts    = (const float*)d_in[1];
    const float* gm      = (const float*)d_in[2];
    const float* conv_w  = (const float*)d_in[3];
    const float* conv_b  = (const float*)d_in[4];
    const float* t2v_w   = (const float*)d_in[5];
    const float* t2v_phi = (const float*)d_in[6];
    const float* wq_w    = (const float*)d_in[7];
    const float* wq_b    = (const float*)d_in[8];
    const float* wk_w    = (const float*)d_in[9];
    const float* proj_w  = (const float*)d_in[11];
    const float* proj_b  = (const float*)d_in[12];
    const float* g1_w    = (const float*)d_in[13];
    const float* g1_b    = (const float*)d_in[14];
    const float* g2_w    = (const float*)d_in[15];
    const float* g2_b    = (const float*)d_in[16];

    float* out = (float*)d_out;

    float* ws      = (float*)d_ws;
    float* regular = ws;                               // 16384
    float* QWbuf   = regular + D_M * ALPHA;            // 131072  [h][d][a]
    float* interp  = QWbuf + N_HEADS * D_V * ALPHA;    // 131072  [a][m][h]

    prep_kernel<<<D_M + 128, 256, 0, stream>>>(
        x_ts, t_ts, gm, t2v_w, t2v_phi, wq_w, wq_b, wk_w, regular, QWbuf);
    attn_fused_kernel<<<dim3(2, D_M, N_HEADS), 256, 0, stream>>>(
        x_ts, t_ts, t2v_w, t2v_phi, QWbuf, interp);
    final_kernel<<<ALPHA, 256, 0, stream>>>(
        regular, interp, conv_w, conv_b, proj_w, proj_b,
        g1_w, g1_b, g2_w, g2_b, out);
}

// Round 11
// 70.593 us; speedup vs baseline: 1.7890x; 1.3552x over previous
//
#include <hip/hip_runtime.h>

#define D_M     64
#define L_OBS   256
#define ALPHA   256
#define D_H     256
#define D_V     64
#define N_HEADS 8

typedef _Float16 half8 __attribute__((ext_vector_type(8)));
typedef float    f32x4 __attribute__((ext_vector_type(4)));

// ---------------------------------------------------------------------------
// Kernel 1: prep. Blocks 0..63: per-row imputation (wave-scan cummax).
// Blocks 64..191: per-(h, 16-a-chunk) fold: Qa = theta_a.wq^T + wq_b,
// QW[d][a] = Qa.wk[.][d]. (a-constant score terms dropped: softmax shift-inv.)
// ---------------------------------------------------------------------------
__global__ __launch_bounds__(256) void prep_kernel(
    const float* __restrict__ x_ts, const float* __restrict__ t_ts,
    const float* __restrict__ gm,
    const float* __restrict__ t2v_w, const float* __restrict__ t2v_phi,
    const float* __restrict__ wq_w, const float* __restrict__ wq_b,
    const float* __restrict__ wk_w,
    float* __restrict__ regular, float* __restrict__ QWbuf)
{
    const int tid = threadIdx.x;

    __shared__ int   last[ALPHA];
    __shared__ float vals[ALPHA];
    __shared__ int   wtot[4];
    __shared__ __align__(16) float wq_s[D_V][68];
    __shared__ __align__(16) float thA[16][68];
    __shared__ __align__(16) float QaT[16][68];

    if (blockIdx.x < D_M) {
        // ---------------- imputation ----------------
        const int m  = blockIdx.x;
        const int l  = tid;
        const int wv = tid >> 6;
        const int ln = tid & 63;
        last[l] = -1;
        __syncthreads();
        float x = x_ts[m * L_OBS + l];
        float t = t_ts[m * L_OBS + l];
        bool valid = (x == x) && (t >= 0.0f);
        int idx = (int)t;
        if (valid && idx < ALPHA) atomicMax(&last[idx], l);
        __syncthreads();
        int li = last[l];
        vals[l] = (li >= 0) ? x_ts[m * L_OBS + li] : 0.0f;
        int p = (li >= 0) ? l : -1;
        #pragma unroll
        for (int s = 1; s < 64; s <<= 1) {
            int q = __shfl_up(p, s);
            if (ln >= s && q > p) p = q;
        }
        if (ln == 63) wtot[wv] = p;
        __syncthreads();
        int pre = -1;
        for (int w = 0; w < 4; w++)
            if (w < wv && wtot[w] > pre) pre = wtot[w];
        int lp = (pre > p) ? pre : p;
        regular[m * ALPHA + l] = (lp >= 0) ? vals[lp] : gm[m];
    } else {
        // ---------------- weight fold + QW for 16 a ----------------
        const int pb = blockIdx.x - D_M;   // 0..127
        const int h  = pb >> 4;
        const int a0 = (pb & 15) * 16;

        {
            const float4* w4 = (const float4*)(wq_w + h * D_V * D_V);
            #pragma unroll
            for (int i = 0; i < 4; i++) {
                int f = i * 256 + tid;
                float4 v = w4[f];
                int e = f >> 4, c = (f & 15) * 4;
                *(float4*)&wq_s[e][c] = v;
            }
        }
        {
            int al = tid >> 4, j0 = (tid & 15) * 4;
            float tv = (float)(a0 + al);
            #pragma unroll
            for (int j = 0; j < 4; j++) {
                int d = j0 + j;
                float f = t2v_w[h * D_V + d] * tv + t2v_phi[h * D_V + d];
                thA[al][d] = (d == 0) ? f : __sinf(f);
            }
        }
        __syncthreads();

        // Phase A: QaT[a][e] = thA[a] . wq_s[e] + wq_b[e]
        {
            const int e  = tid >> 2;
            const int ap = tid & 3;
            float accA[4] = {0.f, 0.f, 0.f, 0.f};
            const float4* wrow = (const float4*)&wq_s[e][0];
            #pragma unroll
            for (int j = 0; j < 16; j++) {
                float4 w = wrow[j];
                #pragma unroll
                for (int k = 0; k < 4; k++) {
                    float4 tv = *(const float4*)&thA[ap + 4 * k][j * 4];
                    accA[k] += w.x * tv.x + w.y * tv.y + w.z * tv.z + w.w * tv.w;
                }
            }
            float bq = wq_b[h * D_V + e];
            #pragma unroll
            for (int k = 0; k < 4; k++) QaT[ap + 4 * k][e] = accA[k] + bq;
        }
        __syncthreads();

        // Phase B: QW[d][a] = sum_e QaT[a][e] * wk_w[h][e][d]
        {
            const int d  = tid >> 2;
            const int ap = tid & 3;
            float accB[4] = {0.f, 0.f, 0.f, 0.f};
            #pragma unroll 4
            for (int e4 = 0; e4 < 16; e4++) {
                const float* wkp = &wk_w[(h * D_V + e4 * 4) * D_V + d];
                float w0 = wkp[0];
                float w1 = wkp[D_V];
                float w2 = wkp[2 * D_V];
                float w3 = wkp[3 * D_V];
                #pragma unroll
                for (int k = 0; k < 4; k++) {
                    float4 qv = *(const float4*)&QaT[ap + 4 * k][e4 * 4];
                    accB[k] += qv.x * w0 + qv.y * w1 + qv.z * w2 + qv.w * w3;
                }
            }
            #pragma unroll
            for (int k = 0; k < 4; k++)
                QWbuf[h * D_V * ALPHA + d * ALPHA + a0 + ap + 4 * k] = accB[k];
        }
    }
}

// ---------------------------------------------------------------------------
// Kernel 2: mTAND attention via MFMA (f16, 3-term split precision) with the
// huge d=0 linear term handled EXACTLY in fp32 as rank-1 C-init.
//   S[a][l] = QW[0][a]*(w0*t[l]+phi0)  (fp32, C-init)
//           + sum_{d=1..63} QW[d][a]*sin(w[d]*t[l]+phi[d])   (f16 MFMA:
//             Ah*Bh + Ah*Br + Ar*Bh; residuals = x - f16(x))
// Slot->d assignment is permutation-proof: A and B use the same slot formula,
// so any lane->k mapping mismatch cancels in the dot product; d=0 excluded by
// RANGE (d = 1..64, slot d==64 zero-padded on A).
// Block = (ah,m,h), 256 thr, 4 waves x 2 a-tiles; ZERO barriers in main loop
// (theta built per-lane in registers, A staged in registers once).
// C/D layout (m89-verified): col = lane&15, row = (lane>>4)*4 + reg.
// Online softmax per D-row, lane-local over lt; one 16-lane merge at end.
// ---------------------------------------------------------------------------
__global__ __launch_bounds__(256) void attn_mfma_kernel(
    const float* __restrict__ x_ts, const float* __restrict__ t_ts,
    const float* __restrict__ t2v_w, const float* __restrict__ t2v_phi,
    const float* __restrict__ QWbuf, float* __restrict__ interp)
{
    const int ah  = blockIdx.x;          // a-half (128 a)
    const int m   = blockIdx.y;
    const int h   = blockIdx.z;
    const int tid = threadIdx.x;
    const int wv  = tid >> 6;
    const int ln  = tid & 63;
    const int lg  = ln >> 4;             // lane group (0..3)
    const int lc  = ln & 15;             // col-in-tile / row-in-tile index
    const int abase = ah * 128;

    __shared__ float t_sh[L_OBS], x_sh[L_OBS], mk_sh[L_OBS];
    __shared__ float w_sh[D_V], phi_sh[D_V];

    {
        float x = x_ts[m * L_OBS + tid];
        float t = t_ts[m * L_OBS + tid];
        bool v = (x == x) && (t >= 0.0f);
        x_sh[tid]  = v ? x : 0.0f;
        t_sh[tid]  = v ? t : 0.0f;
        mk_sh[tid] = v ? 0.0f : -1.0e9f;
    }
    if (tid < D_V)          w_sh[tid]         = t2v_w[h * D_V + tid];
    else if (tid < 2 * D_V) phi_sh[tid - D_V] = t2v_phi[h * D_V + tid - D_V];
    __syncthreads();

    const float* __restrict__ QWh = QWbuf + h * D_V * ALPHA;

    // ---- stage A fragments (hi + residual) for this wave's 2 a-tiles ----
    half8 ahf[2][2], arf[2][2];
    float qw0[2][4];
    #pragma unroll
    for (int at = 0; at < 2; at++) {
        const int a = abase + (wv * 2 + at) * 16 + lc;   // A row (lane&15)
        #pragma unroll
        for (int kb = 0; kb < 2; kb++) {
            #pragma unroll
            for (int j = 0; j < 8; j++) {
                int d = 1 + kb * 32 + ((j >> 2) << 4) + (lg << 2) + (j & 3);
                float q = (d < D_V) ? QWh[d * ALPHA + a] : 0.0f;
                _Float16 qh = (_Float16)q;
                ahf[at][kb][j] = qh;
                arf[at][kb][j] = (_Float16)(q - (float)qh);
            }
        }
        const int arow = abase + (wv * 2 + at) * 16 + lg * 4;  // D rows
        #pragma unroll
        for (int r = 0; r < 4; r++) qw0[at][r] = QWh[arow + r];
    }

    const float w0 = w_sh[0], p0 = phi_sh[0];
    const float SCALE2 = 0.18033688011112042f;   // 0.125 * log2(e)

    float mrun[2][4], ssum[2][4], axs[2][4];
    #pragma unroll
    for (int at = 0; at < 2; at++)
        #pragma unroll
        for (int r = 0; r < 4; r++) {
            mrun[at][r] = -3.0e38f; ssum[at][r] = 0.0f; axs[at][r] = 0.0f;
        }

    // ---- main loop over 16 l-tiles: no barriers ----
    for (int lt = 0; lt < 16; lt++) {
        const int l = lt * 16 + lc;      // B col == D col for this lane
        const float tv  = t_sh[l];
        const float xv  = x_sh[l];
        const float mkv = mk_sh[l];
        const float tau = fmaf(w0, tv, p0);   // theta0[l], exact

        half8 bh[2], br[2];
        #pragma unroll
        for (int kb = 0; kb < 2; kb++) {
            #pragma unroll
            for (int j = 0; j < 8; j++) {
                int d = (1 + kb * 32 + ((j >> 2) << 4) + (lg << 2) + (j & 3)) & 63;
                // d==64 wraps to 0: junk-but-finite sin; paired A slot is 0.
                float sv = __sinf(fmaf(w_sh[d], tv, phi_sh[d]));
                _Float16 sh_ = (_Float16)sv;
                bh[kb][j] = sh_;
                br[kb][j] = (_Float16)(sv - (float)sh_);
            }
        }

        #pragma unroll
        for (int at = 0; at < 2; at++) {
            f32x4 acc;
            #pragma unroll
            for (int r = 0; r < 4; r++) acc[r] = qw0[at][r] * tau;  // exact d=0
            #pragma unroll
            for (int kb = 0; kb < 2; kb++) {
                acc = __builtin_amdgcn_mfma_f32_16x16x32_f16(ahf[at][kb], bh[kb], acc, 0, 0, 0);
                acc = __builtin_amdgcn_mfma_f32_16x16x32_f16(ahf[at][kb], br[kb], acc, 0, 0, 0);
                acc = __builtin_amdgcn_mfma_f32_16x16x32_f16(arf[at][kb], bh[kb], acc, 0, 0, 0);
            }
            // online softmax per D-row (lane-local; rows = independent a)
            #pragma unroll
            for (int r = 0; r < 4; r++) {
                float s    = fmaf(acc[r], SCALE2, mkv);
                float mnew = fmaxf(mrun[at][r], s);
                float scl  = __builtin_amdgcn_exp2f(mrun[at][r] - mnew);
                float p    = __builtin_amdgcn_exp2f(s - mnew);
                ssum[at][r] = fmaf(ssum[at][r], scl, p);
                axs[at][r]  = fmaf(axs[at][r],  scl, p * xv);
                mrun[at][r] = mnew;
            }
        }
    }

    // ---- merge across the 16 lc lanes (same D rows), write interp ----
    #pragma unroll
    for (int at = 0; at < 2; at++) {
        #pragma unroll
        for (int r = 0; r < 4; r++) {
            float m0 = mrun[at][r];
            m0 = fmaxf(m0, __shfl_xor(m0, 1));
            m0 = fmaxf(m0, __shfl_xor(m0, 2));
            m0 = fmaxf(m0, __shfl_xor(m0, 4));
            m0 = fmaxf(m0, __shfl_xor(m0, 8));
            float f = __builtin_amdgcn_exp2f(mrun[at][r] - m0);
            float S = ssum[at][r] * f;
            float A = axs[at][r] * f;
            S += __shfl_xor(S, 1); A += __shfl_xor(A, 1);
            S += __shfl_xor(S, 2); A += __shfl_xor(A, 2);
            S += __shfl_xor(S, 4); A += __shfl_xor(A, 4);
            S += __shfl_xor(S, 8); A += __shfl_xor(A, 8);
            if (lc == 0) {
                int a = abase + (wv * 2 + at) * 16 + lg * 4 + r;
                interp[a * (D_M * N_HEADS) + m * N_HEADS + h] = A / S;
            }
        }
    }
}

// ---------------------------------------------------------------------------
// Kernel 3: fused e_imp + e_attn + gate MLP + output. Block per a, 256 thr.
// ---------------------------------------------------------------------------
__global__ __launch_bounds__(256) void final_kernel(
    const float* __restrict__ regular, const float* __restrict__ interp,
    const float* __restrict__ conv_w, const float* __restrict__ conv_b,
    const float* __restrict__ proj_w, const float* __restrict__ proj_b,
    const float* __restrict__ g1_w, const float* __restrict__ g1_b,
    const float* __restrict__ g2_w, const float* __restrict__ g2_b,
    float* __restrict__ out)
{
    const int a = blockIdx.x;
    const int tid = threadIdx.x;
    __shared__ float isum_s[N_HEADS];
    __shared__ __align__(16) float col[D_M];
    __shared__ __align__(16) float c_s[2 * D_H];
    __shared__ __align__(16) float h_s[D_H];

    if (tid < 64) {
        const float4* i4 = (const float4*)&interp[a * (D_M * N_HEADS) + tid * 8];
        float4 v0 = i4[0], v1 = i4[1];
        float v[8] = {v0.x, v0.y, v0.z, v0.w, v1.x, v1.y, v1.z, v1.w};
        #pragma unroll
        for (int s = 1; s < 64; s <<= 1) {
            #pragma unroll
            for (int j = 0; j < 8; j++) v[j] += __shfl_xor(v[j], s);
        }
        if (tid == 0) {
            #pragma unroll
            for (int j = 0; j < 8; j++) isum_s[j] = v[j];
        }
    } else if (tid < 128) {
        col[tid - 64] = regular[(tid - 64) * ALPHA + a];
    }
    __syncthreads();

    float vattn;
    {
        const float4* p4 = (const float4*)&proj_w[tid * N_HEADS];
        float4 v0 = p4[0], v1 = p4[1];
        float sum = v0.x * isum_s[0] + v0.y * isum_s[1] + v0.z * isum_s[2]
                  + v0.w * isum_s[3] + v1.x * isum_s[4] + v1.y * isum_s[5]
                  + v1.z * isum_s[6] + v1.w * isum_s[7];
        vattn = proj_b[tid] + sum * (1.0f / 64.0f);
    }
    float vimp;
    {
        const float4* row = (const float4*)&conv_w[tid * D_M];
        const float4* c4  = (const float4*)col;
        float s0 = 0.f, s1 = 0.f, s2 = 0.f, s3 = 0.f;
        #pragma unroll
        for (int i = 0; i < D_M / 4; i++) {
            float4 r = row[i]; float4 c = c4[i];
            s0 += r.x * c.x; s1 += r.y * c.y; s2 += r.z * c.z; s3 += r.w * c.w;
        }
        vimp = conv_b[tid] + ((s0 + s1) + (s2 + s3));
    }
    c_s[tid]       = vimp;
    c_s[D_H + tid] = vattn;
    __syncthreads();

    {
        const float4* grow = (const float4*)&g1_w[tid * 2 * D_H];
        const float4* c4 = (const float4*)c_s;
        float s0 = 0.f, s1 = 0.f, s2 = 0.f, s3 = 0.f;
        #pragma unroll 8
        for (int i = 0; i < (2 * D_H) / 4; i++) {
            float4 g = grow[i]; float4 c = c4[i];
            s0 += g.x * c.x; s1 += g.y * c.y; s2 += g.z * c.z; s3 += g.w * c.w;
        }
        float hid = g1_b[tid] + ((s0 + s1) + (s2 + s3));
        h_s[tid] = fmaxf(hid, 0.0f);
    }
    __syncthreads();
    {
        const float4* grow = (const float4*)&g2_w[tid * D_H];
        const float4* h4 = (const float4*)h_s;
        float s0 = 0.f, s1 = 0.f, s2 = 0.f, s3 = 0.f;
        #pragma unroll 8
        for (int i = 0; i < D_H / 4; i++) {
            float4 g = grow[i]; float4 hh = h4[i];
            s0 += g.x * hh.x; s1 += g.y * hh.y; s2 += g.z * hh.z; s3 += g.w * hh.w;
        }
        float z = g2_b[tid] + ((s0 + s1) + (s2 + s3));
        float gate = 1.0f / (1.0f + __expf(-z));
        out[a * D_H + tid] = gate * vimp + (1.0f - gate) * vattn;
    }
}

// ---------------------------------------------------------------------------
extern "C" void kernel_launch(void* const* d_in, const int* in_sizes, int n_in,
                              void* d_out, int out_size, void* d_ws, size_t ws_size,
                              hipStream_t stream)
{
    (void)in_sizes; (void)n_in; (void)out_size; (void)ws_size;

    const float* x_ts    = (const float*)d_in[0];
    const float* t_ts    = (const float*)d_in[1];
    const float* gm      = (const float*)d_in[2];
    const float* conv_w  = (const float*)d_in[3];
    const float* conv_b  = (const float*)d_in[4];
    const float* t2v_w   = (const float*)d_in[5];
    const float* t2v_phi = (const float*)d_in[6];
    const float* wq_w    = (const float*)d_in[7];
    const float* wq_b    = (const float*)d_in[8];
    const float* wk_w    = (const float*)d_in[9];
    const float* proj_w  = (const float*)d_in[11];
    const float* proj_b  = (const float*)d_in[12];
    const float* g1_w    = (const float*)d_in[13];
    const float* g1_b    = (const float*)d_in[14];
    const float* g2_w    = (const float*)d_in[15];
    const float* g2_b    = (const float*)d_in[16];

    float* out = (float*)d_out;

    float* ws      = (float*)d_ws;
    float* regular = ws;                               // 16384
    float* QWbuf   = regular + D_M * ALPHA;            // 131072  [h][d][a]
    float* interp  = QWbuf + N_HEADS * D_V * ALPHA;    // 131072  [a][m][h]

    prep_kernel<<<D_M + 128, 256, 0, stream>>>(
        x_ts, t_ts, gm, t2v_w, t2v_phi, wq_w, wq_b, wk_w, regular, QWbuf);
    attn_mfma_kernel<<<dim3(2, D_M, N_HEADS), 256, 0, stream>>>(
        x_ts, t_ts, t2v_w, t2v_phi, QWbuf, interp);
    final_kernel<<<ALPHA, 256, 0, stream>>>(
        regular, interp, conv_w, conv_b, proj_w, proj_b,
        g1_w, g1_b, g2_w, g2_b, out);
}

// Round 12
// 60.889 us; speedup vs baseline: 2.0741x; 1.1594x over previous
//
#include <hip/hip_runtime.h>

#define D_M     64
#define L_OBS   256
#define ALPHA   256
#define D_H     256
#define D_V     64
#define N_HEADS 8

typedef _Float16 half8 __attribute__((ext_vector_type(8)));
typedef float    f32x4 __attribute__((ext_vector_type(4)));

// ---------------------------------------------------------------------------
// Kernel 1: prep. Blocks 0..63: per-row imputation (wave-scan cummax).
// Blocks 64..191: per-(h, 16-a-chunk) fold: Qa = theta_a.wq^T + wq_b,
// QW[d][a] = Qa.wk[.][d]; also QWabs[a] = sum_{d>=1} |QW[d][a]| (softmax bound).
// ---------------------------------------------------------------------------
__global__ __launch_bounds__(256) void prep_kernel(
    const float* __restrict__ x_ts, const float* __restrict__ t_ts,
    const float* __restrict__ gm,
    const float* __restrict__ t2v_w, const float* __restrict__ t2v_phi,
    const float* __restrict__ wq_w, const float* __restrict__ wq_b,
    const float* __restrict__ wk_w,
    float* __restrict__ regular, float* __restrict__ QWbuf,
    float* __restrict__ QWabsG)
{
    const int tid = threadIdx.x;

    __shared__ int   last[ALPHA];
    __shared__ float vals[ALPHA];
    __shared__ int   wtot[4];
    __shared__ __align__(16) float wq_s[D_V][68];
    __shared__ __align__(16) float thA[16][68];
    __shared__ __align__(16) float QaT[16][68];

    if (blockIdx.x < D_M) {
        // ---------------- imputation ----------------
        const int m  = blockIdx.x;
        const int l  = tid;
        const int wv = tid >> 6;
        const int ln = tid & 63;
        last[l] = -1;
        __syncthreads();
        float x = x_ts[m * L_OBS + l];
        float t = t_ts[m * L_OBS + l];
        bool valid = (x == x) && (t >= 0.0f);
        int idx = (int)t;
        if (valid && idx < ALPHA) atomicMax(&last[idx], l);
        __syncthreads();
        int li = last[l];
        vals[l] = (li >= 0) ? x_ts[m * L_OBS + li] : 0.0f;
        int p = (li >= 0) ? l : -1;
        #pragma unroll
        for (int s = 1; s < 64; s <<= 1) {
            int q = __shfl_up(p, s);
            if (ln >= s && q > p) p = q;
        }
        if (ln == 63) wtot[wv] = p;
        __syncthreads();
        int pre = -1;
        for (int w = 0; w < 4; w++)
            if (w < wv && wtot[w] > pre) pre = wtot[w];
        int lp = (pre > p) ? pre : p;
        regular[m * ALPHA + l] = (lp >= 0) ? vals[lp] : gm[m];
    } else {
        // ---------------- weight fold + QW for 16 a ----------------
        const int pb = blockIdx.x - D_M;   // 0..127
        const int h  = pb >> 4;
        const int a0 = (pb & 15) * 16;

        {
            const float4* w4 = (const float4*)(wq_w + h * D_V * D_V);
            #pragma unroll
            for (int i = 0; i < 4; i++) {
                int f = i * 256 + tid;
                float4 v = w4[f];
                int e = f >> 4, c = (f & 15) * 4;
                *(float4*)&wq_s[e][c] = v;
            }
        }
        {
            int al = tid >> 4, j0 = (tid & 15) * 4;
            float tv = (float)(a0 + al);
            #pragma unroll
            for (int j = 0; j < 4; j++) {
                int d = j0 + j;
                float f = t2v_w[h * D_V + d] * tv + t2v_phi[h * D_V + d];
                thA[al][d] = (d == 0) ? f : __sinf(f);
            }
        }
        __syncthreads();

        // Phase A: QaT[a][e] = thA[a] . wq_s[e] + wq_b[e]
        {
            const int e  = tid >> 2;
            const int ap = tid & 3;
            float accA[4] = {0.f, 0.f, 0.f, 0.f};
            const float4* wrow = (const float4*)&wq_s[e][0];
            #pragma unroll
            for (int j = 0; j < 16; j++) {
                float4 w = wrow[j];
                #pragma unroll
                for (int k = 0; k < 4; k++) {
                    float4 tv = *(const float4*)&thA[ap + 4 * k][j * 4];
                    accA[k] += w.x * tv.x + w.y * tv.y + w.z * tv.z + w.w * tv.w;
                }
            }
            float bq = wq_b[h * D_V + e];
            #pragma unroll
            for (int k = 0; k < 4; k++) QaT[ap + 4 * k][e] = accA[k] + bq;
        }
        __syncthreads();

        // Phase B: QW[d][a] = sum_e QaT[a][e] * wk_w[h][e][d]
        const int d  = tid >> 2;
        const int ap = tid & 3;
        float accB[4] = {0.f, 0.f, 0.f, 0.f};
        #pragma unroll 4
        for (int e4 = 0; e4 < 16; e4++) {
            const float* wkp = &wk_w[(h * D_V + e4 * 4) * D_V + d];
            float w0 = wkp[0];
            float w1 = wkp[D_V];
            float w2 = wkp[2 * D_V];
            float w3 = wkp[3 * D_V];
            #pragma unroll
            for (int k = 0; k < 4; k++) {
                float4 qv = *(const float4*)&QaT[ap + 4 * k][e4 * 4];
                accB[k] += qv.x * w0 + qv.y * w1 + qv.z * w2 + qv.w * w3;
            }
        }
        #pragma unroll
        for (int k = 0; k < 4; k++)
            QWbuf[h * D_V * ALPHA + d * ALPHA + a0 + ap + 4 * k] = accB[k];

        // QWabs reduction: wq_s reused as red[d][a-local]
        __syncthreads();   // phase-A reads of wq_s long done; QaT reads done
        #pragma unroll
        for (int k = 0; k < 4; k++)
            wq_s[d][ap + 4 * k] = (d == 0) ? 0.0f : fabsf(accB[k]);
        __syncthreads();
        if (tid < 16) {
            float s = 0.0f;
            #pragma unroll 8
            for (int dd = 0; dd < D_V; dd++) s += wq_s[dd][tid];
            QWabsG[h * ALPHA + a0 + tid] = s;
        }
    }
}

// ---------------------------------------------------------------------------
// Kernel 2: mTAND attention via MFMA, block per (m,h), 256 thr = 4 waves,
// each wave owns 4 a-tiles (64 a). Per 16-l tile:
//   writers: all 256 thr compute the 1024 sins ONCE -> LDS f16 frag buffer
//            (hi + residual), laid out in exact MFMA B-fragment order
//   readers: each lane ds_read_b128 x4 -> 24 MFMA (3-term split precision)
//   softmax: BOUND-SHIFTED (no online max): p = exp2(acc*S + mk - sB[a]),
//            sB = upper bound from QW0*tau extremes + sum|QW| (prep).
// d=0 linear term exact in fp32 as C-init (rank-1). d-slot formula identical
// on A and B sides (permutation-proof). Guard: fully-invalid row -> 0.
// ---------------------------------------------------------------------------
__global__ __launch_bounds__(256) void attn_mfma_kernel(
    const float* __restrict__ x_ts, const float* __restrict__ t_ts,
    const float* __restrict__ t2v_w, const float* __restrict__ t2v_phi,
    const float* __restrict__ QWbuf, const float* __restrict__ QWabsG,
    float* __restrict__ interp)
{
    const int m   = blockIdx.x;
    const int h   = blockIdx.y;
    const int tid = threadIdx.x;
    const int wv  = tid >> 6;
    const int ln  = tid & 63;
    const int lg  = ln >> 4;             // lane group (0..3)
    const int lc  = ln & 15;             // B col / A row within tile

    __shared__ float t_sh[L_OBS], x_sh[L_OBS], mk_sh[L_OBS];
    __shared__ float w_sh[D_V], phi_sh[D_V];
    __shared__ __align__(16) _Float16 hiB[1024];   // 2 KiB frag hi
    __shared__ __align__(16) _Float16 reB[1024];   // 2 KiB frag residual
    __shared__ float red_s[8];

    {
        float x = x_ts[m * L_OBS + tid];
        float t = t_ts[m * L_OBS + tid];
        bool v = (x == x) && (t >= 0.0f);
        x_sh[tid]  = v ? x : 0.0f;
        t_sh[tid]  = v ? t : 0.0f;
        mk_sh[tid] = v ? 0.0f : -1.0e9f;
        // valid-t extremes (wave reduce -> LDS)
        float tmx = v ? t : -3.0e38f;
        float tmn = v ? t : 3.0e38f;
        #pragma unroll
        for (int s = 1; s < 64; s <<= 1) {
            tmx = fmaxf(tmx, __shfl_xor(tmx, s));
            tmn = fminf(tmn, __shfl_xor(tmn, s));
        }
        if (ln == 0) { red_s[wv] = tmx; red_s[4 + wv] = tmn; }
    }
    if (tid < D_V)          w_sh[tid]         = t2v_w[h * D_V + tid];
    else if (tid < 2 * D_V) phi_sh[tid - D_V] = t2v_phi[h * D_V + tid - D_V];
    __syncthreads();

    const float tmaxv = fmaxf(fmaxf(red_s[0], red_s[1]), fmaxf(red_s[2], red_s[3]));
    const float tminv = fminf(fminf(red_s[4], red_s[5]), fminf(red_s[6], red_s[7]));
    const bool  anyv  = tmaxv > -1.0e37f;

    const float* __restrict__ QWh = QWbuf + h * D_V * ALPHA;
    const float w0 = w_sh[0], p0 = phi_sh[0];
    const float SCALE2 = 0.18033688011112042f;   // 0.125 * log2(e)

    // ---- stage A fragments (hi + residual) + row bounds for 4 a-tiles ----
    half8 ahf[4][2], arf[4][2];
    float qw0[4][4], sB[4][4];
    #pragma unroll
    for (int at = 0; at < 4; at++) {
        const int abase = wv * 64 + at * 16;
        const int arowA = abase + lc;
        #pragma unroll
        for (int kb = 0; kb < 2; kb++) {
            #pragma unroll
            for (int j = 0; j < 8; j++) {
                int d = 1 + kb * 32 + ((j >> 2) << 4) + (lg << 2) + (j & 3);
                float q = (d < D_V) ? QWh[d * ALPHA + arowA] : 0.0f;
                _Float16 qh = (_Float16)q;
                ahf[at][kb][j] = qh;
                arf[at][kb][j] = (_Float16)(q - (float)qh);
            }
        }
        const int arowD = abase + lg * 4;
        #pragma unroll
        for (int r = 0; r < 4; r++) {
            float q0 = QWh[arowD + r];
            qw0[at][r] = q0;
            float u = q0 * w0;
            float lin = q0 * p0 + fmaxf(u * tmaxv, u * tminv);
            sB[at][r] = SCALE2 * (lin + QWabsG[h * ALPHA + arowD + r]);
        }
    }

    float ssum[4][4], axs[4][4];
    #pragma unroll
    for (int at = 0; at < 4; at++)
        #pragma unroll
        for (int r = 0; r < 4; r++) { ssum[at][r] = 0.0f; axs[at][r] = 0.0f; }

    // writer-role constants
    const int wc  = tid >> 5;                 // combo = kb*4+lg, 0..7
    const int lcw = (tid >> 1) & 15;          // l within tile
    const int dB  = 1 + (wc >> 2) * 32 + (wc & 3) * 4 + ((tid & 1) << 4);

    // ---- main loop over 16 l-tiles ----
    for (int lt = 0; lt < 16; lt++) {
        if (lt) __syncthreads();   // previous tile's reads complete
        // writer: 4 sins -> hi/res f16 pairs, 8B contiguous per thread
        {
            float tvw = t_sh[lt * 16 + lcw];
            float s0 = __sinf(fmaf(w_sh[(dB + 0) & 63], tvw, phi_sh[(dB + 0) & 63]));
            float s1 = __sinf(fmaf(w_sh[(dB + 1) & 63], tvw, phi_sh[(dB + 1) & 63]));
            float s2 = __sinf(fmaf(w_sh[(dB + 2) & 63], tvw, phi_sh[(dB + 2) & 63]));
            float s3 = __sinf(fmaf(w_sh[(dB + 3) & 63], tvw, phi_sh[(dB + 3) & 63]));
            union { _Float16 hv[4]; float2 f2; } hw, rw;
            hw.hv[0] = (_Float16)s0; hw.hv[1] = (_Float16)s1;
            hw.hv[2] = (_Float16)s2; hw.hv[3] = (_Float16)s3;
            rw.hv[0] = (_Float16)(s0 - (float)hw.hv[0]);
            rw.hv[1] = (_Float16)(s1 - (float)hw.hv[1]);
            rw.hv[2] = (_Float16)(s2 - (float)hw.hv[2]);
            rw.hv[3] = (_Float16)(s3 - (float)hw.hv[3]);
            *(float2*)&hiB[tid * 4] = hw.f2;
            *(float2*)&reB[tid * 4] = rw.f2;
        }
        __syncthreads();
        // reader: fragments + MFMA + bound-softmax
        const int l = lt * 16 + lc;
        const float tv  = t_sh[l];
        const float xv  = x_sh[l];
        const float mkv = mk_sh[l];
        const float tau = fmaf(w0, tv, p0);

        half8 bh[2], br[2];
        #pragma unroll
        for (int kb = 0; kb < 2; kb++) {
            int fi = ((kb * 4 + lg) * 16 + lc) * 8;
            bh[kb] = *(const half8*)&hiB[fi];
            br[kb] = *(const half8*)&reB[fi];
        }

        #pragma unroll
        for (int at = 0; at < 4; at++) {
            f32x4 acc;
            #pragma unroll
            for (int r = 0; r < 4; r++) acc[r] = qw0[at][r] * tau;  // exact d=0
            #pragma unroll
            for (int kb = 0; kb < 2; kb++) {
                acc = __builtin_amdgcn_mfma_f32_16x16x32_f16(ahf[at][kb], bh[kb], acc, 0, 0, 0);
                acc = __builtin_amdgcn_mfma_f32_16x16x32_f16(ahf[at][kb], br[kb], acc, 0, 0, 0);
                acc = __builtin_amdgcn_mfma_f32_16x16x32_f16(arf[at][kb], bh[kb], acc, 0, 0, 0);
            }
            #pragma unroll
            for (int r = 0; r < 4; r++) {
                float p = __builtin_amdgcn_exp2f(fmaf(acc[r], SCALE2, mkv) - sB[at][r]);
                ssum[at][r] += p;
                axs[at][r]   = fmaf(p, xv, axs[at][r]);
            }
        }
    }

    // ---- merge across the 16 lc lanes, write interp [a][m][h] ----
    #pragma unroll
    for (int at = 0; at < 4; at++) {
        #pragma unroll
        for (int r = 0; r < 4; r++) {
            float S = ssum[at][r];
            float A = axs[at][r];
            S += __shfl_xor(S, 1); A += __shfl_xor(A, 1);
            S += __shfl_xor(S, 2); A += __shfl_xor(A, 2);
            S += __shfl_xor(S, 4); A += __shfl_xor(A, 4);
            S += __shfl_xor(S, 8); A += __shfl_xor(A, 8);
            if (lc == 0) {
                int a = wv * 64 + at * 16 + lg * 4 + r;
                interp[a * (D_M * N_HEADS) + m * N_HEADS + h] =
                    anyv ? (A / S) : 0.0f;
            }
        }
    }
}

// ---------------------------------------------------------------------------
// Kernel 3: fused e_imp + e_attn + gate MLP + output. Block per a, 256 thr.
// ---------------------------------------------------------------------------
__global__ __launch_bounds__(256) void final_kernel(
    const float* __restrict__ regular, const float* __restrict__ interp,
    const float* __restrict__ conv_w, const float* __restrict__ conv_b,
    const float* __restrict__ proj_w, const float* __restrict__ proj_b,
    const float* __restrict__ g1_w, const float* __restrict__ g1_b,
    const float* __restrict__ g2_w, const float* __restrict__ g2_b,
    float* __restrict__ out)
{
    const int a = blockIdx.x;
    const int tid = threadIdx.x;
    __shared__ float isum_s[N_HEADS];
    __shared__ __align__(16) float col[D_M];
    __shared__ __align__(16) float c_s[2 * D_H];
    __shared__ __align__(16) float h_s[D_H];

    if (tid < 64) {
        const float4* i4 = (const float4*)&interp[a * (D_M * N_HEADS) + tid * 8];
        float4 v0 = i4[0], v1 = i4[1];
        float v[8] = {v0.x, v0.y, v0.z, v0.w, v1.x, v1.y, v1.z, v1.w};
        #pragma unroll
        for (int s = 1; s < 64; s <<= 1) {
            #pragma unroll
            for (int j = 0; j < 8; j++) v[j] += __shfl_xor(v[j], s);
        }
        if (tid == 0) {
            #pragma unroll
            for (int j = 0; j < 8; j++) isum_s[j] = v[j];
        }
    } else if (tid < 128) {
        col[tid - 64] = regular[(tid - 64) * ALPHA + a];
    }
    __syncthreads();

    float vattn;
    {
        const float4* p4 = (const float4*)&proj_w[tid * N_HEADS];
        float4 v0 = p4[0], v1 = p4[1];
        float sum = v0.x * isum_s[0] + v0.y * isum_s[1] + v0.z * isum_s[2]
                  + v0.w * isum_s[3] + v1.x * isum_s[4] + v1.y * isum_s[5]
                  + v1.z * isum_s[6] + v1.w * isum_s[7];
        vattn = proj_b[tid] + sum * (1.0f / 64.0f);
    }
    float vimp;
    {
        const float4* row = (const float4*)&conv_w[tid * D_M];
        const float4* c4  = (const float4*)col;
        float s0 = 0.f, s1 = 0.f, s2 = 0.f, s3 = 0.f;
        #pragma unroll
        for (int i = 0; i < D_M / 4; i++) {
            float4 r = row[i]; float4 c = c4[i];
            s0 += r.x * c.x; s1 += r.y * c.y; s2 += r.z * c.z; s3 += r.w * c.w;
        }
        vimp = conv_b[tid] + ((s0 + s1) + (s2 + s3));
    }
    c_s[tid]       = vimp;
    c_s[D_H + tid] = vattn;
    __syncthreads();

    {
        const float4* grow = (const float4*)&g1_w[tid * 2 * D_H];
        const float4* c4 = (const float4*)c_s;
        float s0 = 0.f, s1 = 0.f, s2 = 0.f, s3 = 0.f;
        #pragma unroll 8
        for (int i = 0; i < (2 * D_H) / 4; i++) {
            float4 g = grow[i]; float4 c = c4[i];
            s0 += g.x * c.x; s1 += g.y * c.y; s2 += g.z * c.z; s3 += g.w * c.w;
        }
        float hid = g1_b[tid] + ((s0 + s1) + (s2 + s3));
        h_s[tid] = fmaxf(hid, 0.0f);
    }
    __syncthreads();
    {
        const float4* grow = (const float4*)&g2_w[tid * D_H];
        const float4* h4 = (const float4*)h_s;
        float s0 = 0.f, s1 = 0.f, s2 = 0.f, s3 = 0.f;
        #pragma unroll 8
        for (int i = 0; i < D_H / 4; i++) {
            float4 g = grow[i]; float4 hh = h4[i];
            s0 += g.x * hh.x; s1 += g.y * hh.y; s2 += g.z * hh.z; s3 += g.w * hh.w;
        }
        float z = g2_b[tid] + ((s0 + s1) + (s2 + s3));
        float gate = 1.0f / (1.0f + __expf(-z));
        out[a * D_H + tid] = gate * vimp + (1.0f - gate) * vattn;
    }
}

// ---------------------------------------------------------------------------
extern "C" void kernel_launch(void* const* d_in, const int* in_sizes, int n_in,
                              void* d_out, int out_size, void* d_ws, size_t ws_size,
                              hipStream_t stream)
{
    (void)in_sizes; (void)n_in; (void)out_size; (void)ws_size;

    const float* x_ts    = (const float*)d_in[0];
    const float* t_ts    = (const float*)d_in[1];
    const float* gm      = (const float*)d_in[2];
    const float* conv_w  = (const float*)d_in[3];
    const float* conv_b  = (const float*)d_in[4];
    const float* t2v_w   = (const float*)d_in[5];
    const float* t2v_phi = (const float*)d_in[6];
    const float* wq_w    = (const float*)d_in[7];
    const float* wq_b    = (const float*)d_in[8];
    const float* wk_w    = (const float*)d_in[9];
    const float* proj_w  = (const float*)d_in[11];
    const float* proj_b  = (const float*)d_in[12];
    const float* g1_w    = (const float*)d_in[13];
    const float* g1_b    = (const float*)d_in[14];
    const float* g2_w    = (const float*)d_in[15];
    const float* g2_b    = (const float*)d_in[16];

    float* out = (float*)d_out;

    float* ws      = (float*)d_ws;
    float* regular = ws;                               // 16384
    float* QWbuf   = regular + D_M * ALPHA;            // 131072  [h][d][a]
    float* interp  = QWbuf + N_HEADS * D_V * ALPHA;    // 131072  [a][m][h]
    float* QWabs   = interp + ALPHA * D_M * N_HEADS;   // 2048    [h][a]

    prep_kernel<<<D_M + 128, 256, 0, stream>>>(
        x_ts, t_ts, gm, t2v_w, t2v_phi, wq_w, wq_b, wk_w,
        regular, QWbuf, QWabs);
    attn_mfma_kernel<<<dim3(D_M, N_HEADS), 256, 0, stream>>>(
        x_ts, t_ts, t2v_w, t2v_phi, QWbuf, QWabs, interp);
    final_kernel<<<ALPHA, 256, 0, stream>>>(
        regular, interp, conv_w, conv_b, proj_w, proj_b,
        g1_w, g1_b, g2_w, g2_b, out);
}